// Round 14
// baseline (217.021 us; speedup 1.0000x reference)
//
#include <hip/hip_runtime.h>

#define S_LEN 512
#define BATCH 64
#define HDIM  1024
#define TWOH  2048
#define EMB   512
#define KDIM  2560      // 2H + EMB
#define KTOT  3584      // 2H + EMB + H
#define VOUT  32000

// ws layout (float offsets)
#define WS_MS    64
#define WS_CTX   2112                        // f32 [64][16][2048] = 2,097,152 floats
#define WS_GP    WS_CTX                      // gate partials [8][4096][64] f32 — aliases dead ctx
#define WS_RNNB  (WS_CTX + 64*16*2048)       // bf16 [64][3584] = 114,688 floats
#define WS_HB16  (WS_RNNB + 114688)          // bf16 [64][1024] = 32,768 floats

typedef __attribute__((ext_vector_type(8))) short bf16x8;
typedef __attribute__((ext_vector_type(4))) float f32x4;

__device__ __forceinline__ float sigmoidf_(float x) { return 1.f/(1.f+__expf(-x)); }

// RNE float -> bf16 (finite inputs)
__device__ __forceinline__ unsigned short f2bf(float f) {
  union { float f; unsigned u; } v; v.f = f;
  return (unsigned short)((v.u + 0x7fffu + ((v.u >> 16) & 1u)) >> 16);
}

__device__ __forceinline__ bf16x8 cvt_frag(const float4& a, const float4& b) {
  bf16x8 r;
  r[0] = (short)f2bf(a.x); r[1] = (short)f2bf(a.y);
  r[2] = (short)f2bf(a.z); r[3] = (short)f2bf(a.w);
  r[4] = (short)f2bf(b.x); r[5] = (short)f2bf(b.y);
  r[6] = (short)f2bf(b.z); r[7] = (short)f2bf(b.w);
  return r;
}

// K1 v3: single-pass online-softmax context, row-pipelined, hb inline.
__global__ __launch_bounds__(256) void k_attn(const float* __restrict__ enc,
                                              const float* __restrict__ eW,
                                              const float* __restrict__ eb,
                                              const float* __restrict__ hidden,
                                              float* __restrict__ ws_ms,
                                              float* __restrict__ ws_ctx) {
  __shared__ float lds_ms[4][2];
  __shared__ float lds_ctx[4][2048];
  const int lane  = threadIdx.x & 63;
  const int wave  = threadIdx.x >> 6;
  const int chunk = blockIdx.x;   // 0..15
  const int b     = blockIdx.y;   // 0..63

  float hba = 0.f;
  for (int k = lane; k < HDIM; k += 64) hba += hidden[b*HDIM + k] * eW[k];
#pragma unroll
  for (int st = 32; st >= 1; st >>= 1) hba += __shfl_xor(hba, st, 64);
  const float hb = hba + eb[0];

  float4 w4[8];
#pragma unroll
  for (int k = 0; k < 8; ++k)
    w4[k] = *reinterpret_cast<const float4*>(eW + HDIM + 4*lane + 256*k);

  const int s0 = chunk*32 + wave*8;
  const float* base = enc + ((size_t)(s0*BATCH + b))*TWOH + 4*lane;

  float m = 0.f, ssum = 0.f;      // relu => e >= 0
  float4 ctx[8];
#pragma unroll
  for (int k = 0; k < 8; ++k) ctx[k] = make_float4(0.f, 0.f, 0.f, 0.f);

  float4 va[8], vb[8];
#pragma unroll
  for (int k = 0; k < 8; ++k) va[k] = *reinterpret_cast<const float4*>(base + 256*k);

#define ATTN_STEP(VCUR, VNXT, I)                                              \
  {                                                                           \
    if ((I) < 7) {                                                            \
      const float* pn = base + (size_t)((I)+1)*BATCH*TWOH;                    \
      _Pragma("unroll")                                                       \
      for (int k = 0; k < 8; ++k)                                             \
        VNXT[k] = *reinterpret_cast<const float4*>(pn + 256*k);               \
    }                                                                         \
    float a = 0.f;                                                            \
    _Pragma("unroll")                                                         \
    for (int k = 0; k < 8; ++k)                                               \
      a += VCUR[k].x*w4[k].x + VCUR[k].y*w4[k].y +                            \
           VCUR[k].z*w4[k].z + VCUR[k].w*w4[k].w;                             \
    _Pragma("unroll")                                                         \
    for (int st = 1; st < 64; st <<= 1) a += __shfl_xor(a, st, 64);           \
    const float e = fmaxf(a + hb, 0.f);                                       \
    if (e > m) {                                                              \
      const float sc = __expf(m - e);                                         \
      ssum = ssum*sc + 1.f;                                                   \
      _Pragma("unroll")                                                       \
      for (int k = 0; k < 8; ++k) {                                           \
        ctx[k].x = fmaf(ctx[k].x, sc, VCUR[k].x);                             \
        ctx[k].y = fmaf(ctx[k].y, sc, VCUR[k].y);                             \
        ctx[k].z = fmaf(ctx[k].z, sc, VCUR[k].z);                             \
        ctx[k].w = fmaf(ctx[k].w, sc, VCUR[k].w);                             \
      }                                                                       \
      m = e;                                                                  \
    } else {                                                                  \
      const float pw = __expf(e - m);                                         \
      ssum += pw;                                                             \
      _Pragma("unroll")                                                       \
      for (int k = 0; k < 8; ++k) {                                           \
        ctx[k].x = fmaf(pw, VCUR[k].x, ctx[k].x);                             \
        ctx[k].y = fmaf(pw, VCUR[k].y, ctx[k].y);                             \
        ctx[k].z = fmaf(pw, VCUR[k].z, ctx[k].z);                             \
        ctx[k].w = fmaf(pw, VCUR[k].w, ctx[k].w);                             \
      }                                                                       \
    }                                                                         \
  }

  ATTN_STEP(va, vb, 0)
  ATTN_STEP(vb, va, 1)
  ATTN_STEP(va, vb, 2)
  ATTN_STEP(vb, va, 3)
  ATTN_STEP(va, vb, 4)
  ATTN_STEP(vb, va, 5)
  ATTN_STEP(va, vb, 6)
  ATTN_STEP(vb, va, 7)
#undef ATTN_STEP

  if (lane == 0) { lds_ms[wave][0] = m; lds_ms[wave][1] = ssum; }
  __syncthreads();
  const float M = fmaxf(fmaxf(lds_ms[0][0], lds_ms[1][0]),
                        fmaxf(lds_ms[2][0], lds_ms[3][0]));
  const float wsc = __expf(m - M);
  float ssum_c = 0.f;
#pragma unroll
  for (int w = 0; w < 4; ++w) ssum_c += __expf(lds_ms[w][0] - M) * lds_ms[w][1];
#pragma unroll
  for (int k = 0; k < 8; ++k) {
    float4 c = ctx[k];
    c.x *= wsc; c.y *= wsc; c.z *= wsc; c.w *= wsc;
    *reinterpret_cast<float4*>(&lds_ctx[wave][4*lane + 256*k]) = c;
  }
  __syncthreads();
  float* outp = ws_ctx + ((size_t)b*16 + chunk)*TWOH;
  for (int d = threadIdx.x; d < TWOH; d += 256)
    outp[d] = lds_ctx[0][d] + lds_ctx[1][d] + lds_ctx[2][d] + lds_ctx[3][d];
  if (threadIdx.x == 0) {
    ws_ms[((size_t)b*16 + chunk)*2]     = M;
    ws_ms[((size_t)b*16 + chunk)*2 + 1] = ssum_c;
  }
}

// K2 v3: combine 16 chunk-partials; emit bf16 rnnB [b][KTOT] = ctx | emb | hidden.
__global__ __launch_bounds__(256) void k_combine(const float* __restrict__ ws_ms,
                                                 const float* __restrict__ ws_ctx,
                                                 const float* __restrict__ hidden,
                                                 const float* __restrict__ emb_table,
                                                 const int* __restrict__ x,
                                                 unsigned short* __restrict__ rnnB) {
  const int b = blockIdx.x;
  float mc[16], sc[16];
#pragma unroll
  for (int c = 0; c < 16; ++c) {
    mc[c] = ws_ms[(b*16 + c)*2];
    sc[c] = ws_ms[(b*16 + c)*2 + 1];
  }
  float M = mc[0];
#pragma unroll
  for (int c = 1; c < 16; ++c) M = fmaxf(M, mc[c]);
  float wc[16], Ssum = 0.f;
#pragma unroll
  for (int c = 0; c < 16; ++c) { wc[c] = __expf(mc[c] - M); Ssum += wc[c]*sc[c]; }
  const float inv = 1.f / Ssum;
  unsigned short* rb = rnnB + (size_t)b*KTOT;
  for (int d = threadIdx.x; d < TWOH; d += 256) {
    float a = 0.f;
#pragma unroll
    for (int c = 0; c < 16; ++c) a += wc[c] * ws_ctx[((size_t)b*16 + c)*TWOH + d];
    rb[d] = f2bf(a * inv);
  }
  const int xb = x[b];
  for (int e = threadIdx.x; e < EMB; e += 256)
    rb[TWOH + e] = f2bf(emb_table[(size_t)xb*EMB + e]);
  for (int k = threadIdx.x; k < HDIM; k += 256)
    rb[KDIM + k] = f2bf(hidden[b*HDIM + k]);
}

// K3 v5 (R11 best): MFMA gate GEMM, k-loop unrolled x2.
// NOTE: launched TWICE this round (probe; idempotent).
__global__ __launch_bounds__(256) void k_gates(const unsigned short* __restrict__ rnnB,
                                               const float* __restrict__ W_ih,
                                               const float* __restrict__ W_hh,
                                               float* __restrict__ ws_gp) {
  const int lane = threadIdx.x & 63;
  const int wave = threadIdx.x >> 6;
  const int part = blockIdx.x & 7;     // k-part: 448 each
  const int rg   = blockIdx.x >> 3;    // 0..63
  const int row0 = rg*64 + wave*16;
  const int mlo  = lane & 15;
  const int kg   = lane >> 4;
  const int j    = row0 + mlo;

  f32x4 acc0 = {0.f,0.f,0.f,0.f}, acc1 = acc0, acc2 = acc0, acc3 = acc0;

  for (int k0 = 0; k0 < 448; k0 += 64) {
    const int kb0 = part*448 + k0;
    const int kb1 = kb0 + 32;          // 32-chunks never cross KDIM (all %32==0)
    const float* ws0 = (kb0 < KDIM) ? (W_ih + (size_t)j*KDIM + kb0 + kg*8)
                                    : (W_hh + (size_t)j*HDIM + (kb0 - KDIM) + kg*8);
    const float* ws1 = (kb1 < KDIM) ? (W_ih + (size_t)j*KDIM + kb1 + kg*8)
                                    : (W_hh + (size_t)j*HDIM + (kb1 - KDIM) + kg*8);
    const float4 wa0 = *reinterpret_cast<const float4*>(ws0);
    const float4 wb0 = *reinterpret_cast<const float4*>(ws0 + 4);
    const float4 wa1 = *reinterpret_cast<const float4*>(ws1);
    const float4 wb1 = *reinterpret_cast<const float4*>(ws1 + 4);

    const size_t ko0 = (size_t)kb0 + kg*8;
    const size_t ko1 = (size_t)kb1 + kg*8;
    const unsigned short* rp0 = rnnB + (size_t)mlo*KTOT;
    const bf16x8 b00 = *reinterpret_cast<const bf16x8*>(rp0 + ko0);
    const bf16x8 b10 = *reinterpret_cast<const bf16x8*>(rp0 + 16*KTOT + ko0);
    const bf16x8 b20 = *reinterpret_cast<const bf16x8*>(rp0 + 32*KTOT + ko0);
    const bf16x8 b30 = *reinterpret_cast<const bf16x8*>(rp0 + 48*KTOT + ko0);
    const bf16x8 b01 = *reinterpret_cast<const bf16x8*>(rp0 + ko1);
    const bf16x8 b11 = *reinterpret_cast<const bf16x8*>(rp0 + 16*KTOT + ko1);
    const bf16x8 b21 = *reinterpret_cast<const bf16x8*>(rp0 + 32*KTOT + ko1);
    const bf16x8 b31 = *reinterpret_cast<const bf16x8*>(rp0 + 48*KTOT + ko1);

    const bf16x8 af0 = cvt_frag(wa0, wb0);
    const bf16x8 af1 = cvt_frag(wa1, wb1);

    acc0 = __builtin_amdgcn_mfma_f32_16x16x32_bf16(af0, b00, acc0, 0, 0, 0);
    acc1 = __builtin_amdgcn_mfma_f32_16x16x32_bf16(af0, b10, acc1, 0, 0, 0);
    acc2 = __builtin_amdgcn_mfma_f32_16x16x32_bf16(af0, b20, acc2, 0, 0, 0);
    acc3 = __builtin_amdgcn_mfma_f32_16x16x32_bf16(af0, b30, acc3, 0, 0, 0);
    acc0 = __builtin_amdgcn_mfma_f32_16x16x32_bf16(af1, b01, acc0, 0, 0, 0);
    acc1 = __builtin_amdgcn_mfma_f32_16x16x32_bf16(af1, b11, acc1, 0, 0, 0);
    acc2 = __builtin_amdgcn_mfma_f32_16x16x32_bf16(af1, b21, acc2, 0, 0, 0);
    acc3 = __builtin_amdgcn_mfma_f32_16x16x32_bf16(af1, b31, acc3, 0, 0, 0);
  }

  const int mbase = row0 + kg*4;
#define G_ST(ACC, N)                                                          \
  {                                                                           \
    _Pragma("unroll")                                                         \
    for (int jj = 0; jj < 4; ++jj)                                            \
      ws_gp[((size_t)part*4096 + mbase + jj)*64 + ((N)*16 + mlo)] = ACC[jj];  \
  }
  G_ST(acc0, 0) G_ST(acc1, 1) G_ST(acc2, 2) G_ST(acc3, 3)
#undef G_ST
}

// K3b: sum 8 partials + biases, LSTM pointwise; emit h as f32 outs + bf16 hB.
__global__ __launch_bounds__(256) void k_lstm(const float* __restrict__ ws_gp,
                                              const float* __restrict__ b_ih,
                                              const float* __restrict__ b_hh,
                                              const float* __restrict__ cell,
                                              float* __restrict__ out_h,
                                              float* __restrict__ out_c,
                                              unsigned short* __restrict__ hB) {
  const int id = blockIdx.x*256 + threadIdx.x;  // 65536
  const int h = id >> 6, b = id & 63;
  float g[4];
#pragma unroll
  for (int gg = 0; gg < 4; ++gg) {
    const int j = gg*1024 + h;
    float v = b_ih[j] + b_hh[j];
#pragma unroll
    for (int p = 0; p < 8; ++p) v += ws_gp[((size_t)p*4096 + j)*64 + b];
    g[gg] = v;
  }
  const float iv = sigmoidf_(g[0]);
  const float fv = sigmoidf_(g[1]);
  const float gv = tanhf(g[2]);
  const float ov = sigmoidf_(g[3]);
  const float cold = cell[b*HDIM + h];
  const float cn = fmaf(fv, cold, iv*gv);
  const float hn = ov * tanhf(cn);
  out_h[b*HDIM + h] = hn;
  out_c[b*HDIM + h] = cn;
  hB[(size_t)b*HDIM + h] = f2bf(hn);
}

// K4 v8 (R11 best): MFMA fc GEMM, k-loop unrolled x2 (64 k/iter).
// NOTE: launched TWICE this round (probe; idempotent).
__global__ __launch_bounds__(256) void k_fc(const unsigned short* __restrict__ hB,
                                            const float* __restrict__ fc_W,
                                            const float* __restrict__ fc_b,
                                            float* __restrict__ preds) {
  const int lane = threadIdx.x & 63;
  const int wave = threadIdx.x >> 6;
  const int row0 = (blockIdx.x*4 + wave)*16;   // grid 500 -> 32000 rows
  const int mlo  = lane & 15;
  const int kg   = lane >> 4;

  const float* wrow = fc_W + (size_t)(row0 + mlo)*HDIM + kg*8;
  const unsigned short* hp = hB + (size_t)mlo*HDIM + kg*8;

  f32x4 acc0 = {0.f,0.f,0.f,0.f}, acc1 = acc0, acc2 = acc0, acc3 = acc0;

  for (int k0 = 0; k0 < HDIM; k0 += 64) {
    const float4 wa0 = *reinterpret_cast<const float4*>(wrow + k0);
    const float4 wb0 = *reinterpret_cast<const float4*>(wrow + k0 + 4);
    const float4 wa1 = *reinterpret_cast<const float4*>(wrow + k0 + 32);
    const float4 wb1 = *reinterpret_cast<const float4*>(wrow + k0 + 36);

    const bf16x8 b00 = *reinterpret_cast<const bf16x8*>(hp + k0);
    const bf16x8 b10 = *reinterpret_cast<const bf16x8*>(hp + 16*HDIM + k0);
    const bf16x8 b20 = *reinterpret_cast<const bf16x8*>(hp + 32*HDIM + k0);
    const bf16x8 b30 = *reinterpret_cast<const bf16x8*>(hp + 48*HDIM + k0);
    const bf16x8 b01 = *reinterpret_cast<const bf16x8*>(hp + k0 + 32);
    const bf16x8 b11 = *reinterpret_cast<const bf16x8*>(hp + 16*HDIM + k0 + 32);
    const bf16x8 b21 = *reinterpret_cast<const bf16x8*>(hp + 32*HDIM + k0 + 32);
    const bf16x8 b31 = *reinterpret_cast<const bf16x8*>(hp + 48*HDIM + k0 + 32);

    const bf16x8 af0 = cvt_frag(wa0, wb0);
    const bf16x8 af1 = cvt_frag(wa1, wb1);

    acc0 = __builtin_amdgcn_mfma_f32_16x16x32_bf16(af0, b00, acc0, 0, 0, 0);
    acc1 = __builtin_amdgcn_mfma_f32_16x16x32_bf16(af0, b10, acc1, 0, 0, 0);
    acc2 = __builtin_amdgcn_mfma_f32_16x16x32_bf16(af0, b20, acc2, 0, 0, 0);
    acc3 = __builtin_amdgcn_mfma_f32_16x16x32_bf16(af0, b30, acc3, 0, 0, 0);
    acc0 = __builtin_amdgcn_mfma_f32_16x16x32_bf16(af1, b01, acc0, 0, 0, 0);
    acc1 = __builtin_amdgcn_mfma_f32_16x16x32_bf16(af1, b11, acc1, 0, 0, 0);
    acc2 = __builtin_amdgcn_mfma_f32_16x16x32_bf16(af1, b21, acc2, 0, 0, 0);
    acc3 = __builtin_amdgcn_mfma_f32_16x16x32_bf16(af1, b31, acc3, 0, 0, 0);
  }

  const int mbase = row0 + kg*4;
  const float4 bias = make_float4(fc_b[mbase], fc_b[mbase+1],
                                  fc_b[mbase+2], fc_b[mbase+3]);
#define FC_STORE(ACC, N)                                                      \
  {                                                                           \
    float4 st = make_float4(ACC[0] + bias.x, ACC[1] + bias.y,                 \
                            ACC[2] + bias.z, ACC[3] + bias.w);                \
    *reinterpret_cast<float4*>(preds + (size_t)((N)*16 + mlo)*VOUT + mbase) = st; \
  }
  FC_STORE(acc0, 0) FC_STORE(acc1, 1) FC_STORE(acc2, 2) FC_STORE(acc3, 3)
#undef FC_STORE
}

extern "C" void kernel_launch(void* const* d_in, const int* in_sizes, int n_in,
                              void* d_out, int out_size, void* d_ws, size_t ws_size,
                              hipStream_t stream) {
  const int*   x      = (const int*)  d_in[0];
  const float* enc    = (const float*)d_in[1];
  const float* hidden = (const float*)d_in[2];
  const float* cell   = (const float*)d_in[3];
  const float* embt   = (const float*)d_in[4];
  const float* eW     = (const float*)d_in[5];
  const float* eb     = (const float*)d_in[6];
  const float* W_ih   = (const float*)d_in[7];
  const float* W_hh   = (const float*)d_in[8];
  const float* b_ih   = (const float*)d_in[9];
  const float* b_hh   = (const float*)d_in[10];
  const float* fc_W   = (const float*)d_in[11];
  const float* fc_b   = (const float*)d_in[12];

  float* out   = (float*)d_out;
  float* preds = out;                              // 64*32000
  float* out_h = out + (size_t)BATCH*VOUT;         // 64*1024
  float* out_c = out_h + BATCH*HDIM;               // 64*1024
  float* ws    = (float*)d_ws;
  unsigned short* rnnB = (unsigned short*)(ws + WS_RNNB);
  unsigned short* hB   = (unsigned short*)(ws + WS_HB16);

  // TIMING PROBE 2: k_gates and k_fc each launched twice (idempotent).
  // Delta vs R11's 149.2 us measures gates+fc combined duration.
  k_attn<<<dim3(16, 64), 256, 0, stream>>>(enc, eW, eb, hidden, ws + WS_MS, ws + WS_CTX);
  k_combine<<<64, 256, 0, stream>>>(ws + WS_MS, ws + WS_CTX, hidden, embt, x, rnnB);
  k_gates<<<512, 256, 0, stream>>>(rnnB, W_ih, W_hh, ws + WS_GP);
  k_gates<<<512, 256, 0, stream>>>(rnnB, W_ih, W_hh, ws + WS_GP);
  k_lstm<<<256, 256, 0, stream>>>(ws + WS_GP, b_ih, b_hh, cell, out_h, out_c, hB);
  k_fc<<<500, 256, 0, stream>>>(hB, fc_W, fc_b, preds);
  k_fc<<<500, 256, 0, stream>>>(hB, fc_W, fc_b, preds);
}

// Round 15
// 150.940 us; speedup vs baseline: 1.4378x; 1.4378x over previous
//
#include <hip/hip_runtime.h>

#define S_LEN 512
#define BATCH 64
#define HDIM  1024
#define TWOH  2048
#define EMB   512
#define KDIM  2560      // 2H + EMB
#define KTOT  3584      // 2H + EMB + H
#define VOUT  32000

// ws layout (float offsets)
#define WS_MS    64
#define WS_CTX   2112                        // f32 [64][16][2048] = 2,097,152 floats
#define WS_GP    WS_CTX                      // gate partials [8][4096][64] f32 — aliases dead ctx
#define WS_FP    WS_CTX                      // fc part1 partial [64][32000] f32 — reuses ws_gp after lstm
#define WS_RNNB  (WS_CTX + 64*16*2048)       // bf16 [64][3584] = 114,688 floats
#define WS_HB16  (WS_RNNB + 114688)          // bf16 [64][1024] = 32,768 floats

typedef __attribute__((ext_vector_type(8))) short bf16x8;
typedef __attribute__((ext_vector_type(4))) float f32x4;

__device__ __forceinline__ float sigmoidf_(float x) { return 1.f/(1.f+__expf(-x)); }

// RNE float -> bf16 (finite inputs)
__device__ __forceinline__ unsigned short f2bf(float f) {
  union { float f; unsigned u; } v; v.f = f;
  return (unsigned short)((v.u + 0x7fffu + ((v.u >> 16) & 1u)) >> 16);
}

__device__ __forceinline__ bf16x8 cvt_frag(const float4& a, const float4& b) {
  bf16x8 r;
  r[0] = (short)f2bf(a.x); r[1] = (short)f2bf(a.y);
  r[2] = (short)f2bf(a.z); r[3] = (short)f2bf(a.w);
  r[4] = (short)f2bf(b.x); r[5] = (short)f2bf(b.y);
  r[6] = (short)f2bf(b.z); r[7] = (short)f2bf(b.w);
  return r;
}

// K1 v3: single-pass online-softmax context, row-pipelined, hb inline.
__global__ __launch_bounds__(256) void k_attn(const float* __restrict__ enc,
                                              const float* __restrict__ eW,
                                              const float* __restrict__ eb,
                                              const float* __restrict__ hidden,
                                              float* __restrict__ ws_ms,
                                              float* __restrict__ ws_ctx) {
  __shared__ float lds_ms[4][2];
  __shared__ float lds_ctx[4][2048];
  const int lane  = threadIdx.x & 63;
  const int wave  = threadIdx.x >> 6;
  const int chunk = blockIdx.x;   // 0..15
  const int b     = blockIdx.y;   // 0..63

  float hba = 0.f;
  for (int k = lane; k < HDIM; k += 64) hba += hidden[b*HDIM + k] * eW[k];
#pragma unroll
  for (int st = 32; st >= 1; st >>= 1) hba += __shfl_xor(hba, st, 64);
  const float hb = hba + eb[0];

  float4 w4[8];
#pragma unroll
  for (int k = 0; k < 8; ++k)
    w4[k] = *reinterpret_cast<const float4*>(eW + HDIM + 4*lane + 256*k);

  const int s0 = chunk*32 + wave*8;
  const float* base = enc + ((size_t)(s0*BATCH + b))*TWOH + 4*lane;

  float m = 0.f, ssum = 0.f;      // relu => e >= 0
  float4 ctx[8];
#pragma unroll
  for (int k = 0; k < 8; ++k) ctx[k] = make_float4(0.f, 0.f, 0.f, 0.f);

  float4 va[8], vb[8];
#pragma unroll
  for (int k = 0; k < 8; ++k) va[k] = *reinterpret_cast<const float4*>(base + 256*k);

#define ATTN_STEP(VCUR, VNXT, I)                                              \
  {                                                                           \
    if ((I) < 7) {                                                            \
      const float* pn = base + (size_t)((I)+1)*BATCH*TWOH;                    \
      _Pragma("unroll")                                                       \
      for (int k = 0; k < 8; ++k)                                             \
        VNXT[k] = *reinterpret_cast<const float4*>(pn + 256*k);               \
    }                                                                         \
    float a = 0.f;                                                            \
    _Pragma("unroll")                                                         \
    for (int k = 0; k < 8; ++k)                                               \
      a += VCUR[k].x*w4[k].x + VCUR[k].y*w4[k].y +                            \
           VCUR[k].z*w4[k].z + VCUR[k].w*w4[k].w;                             \
    _Pragma("unroll")                                                         \
    for (int st = 1; st < 64; st <<= 1) a += __shfl_xor(a, st, 64);           \
    const float e = fmaxf(a + hb, 0.f);                                       \
    if (e > m) {                                                              \
      const float sc = __expf(m - e);                                         \
      ssum = ssum*sc + 1.f;                                                   \
      _Pragma("unroll")                                                       \
      for (int k = 0; k < 8; ++k) {                                           \
        ctx[k].x = fmaf(ctx[k].x, sc, VCUR[k].x);                             \
        ctx[k].y = fmaf(ctx[k].y, sc, VCUR[k].y);                             \
        ctx[k].z = fmaf(ctx[k].z, sc, VCUR[k].z);                             \
        ctx[k].w = fmaf(ctx[k].w, sc, VCUR[k].w);                             \
      }                                                                       \
      m = e;                                                                  \
    } else {                                                                  \
      const float pw = __expf(e - m);                                         \
      ssum += pw;                                                             \
      _Pragma("unroll")                                                       \
      for (int k = 0; k < 8; ++k) {                                           \
        ctx[k].x = fmaf(pw, VCUR[k].x, ctx[k].x);                             \
        ctx[k].y = fmaf(pw, VCUR[k].y, ctx[k].y);                             \
        ctx[k].z = fmaf(pw, VCUR[k].z, ctx[k].z);                             \
        ctx[k].w = fmaf(pw, VCUR[k].w, ctx[k].w);                             \
      }                                                                       \
    }                                                                         \
  }

  ATTN_STEP(va, vb, 0)
  ATTN_STEP(vb, va, 1)
  ATTN_STEP(va, vb, 2)
  ATTN_STEP(vb, va, 3)
  ATTN_STEP(va, vb, 4)
  ATTN_STEP(vb, va, 5)
  ATTN_STEP(va, vb, 6)
  ATTN_STEP(vb, va, 7)
#undef ATTN_STEP

  if (lane == 0) { lds_ms[wave][0] = m; lds_ms[wave][1] = ssum; }
  __syncthreads();
  const float M = fmaxf(fmaxf(lds_ms[0][0], lds_ms[1][0]),
                        fmaxf(lds_ms[2][0], lds_ms[3][0]));
  const float wsc = __expf(m - M);
  float ssum_c = 0.f;
#pragma unroll
  for (int w = 0; w < 4; ++w) ssum_c += __expf(lds_ms[w][0] - M) * lds_ms[w][1];
#pragma unroll
  for (int k = 0; k < 8; ++k) {
    float4 c = ctx[k];
    c.x *= wsc; c.y *= wsc; c.z *= wsc; c.w *= wsc;
    *reinterpret_cast<float4*>(&lds_ctx[wave][4*lane + 256*k]) = c;
  }
  __syncthreads();
  float* outp = ws_ctx + ((size_t)b*16 + chunk)*TWOH;
  for (int d = threadIdx.x; d < TWOH; d += 256)
    outp[d] = lds_ctx[0][d] + lds_ctx[1][d] + lds_ctx[2][d] + lds_ctx[3][d];
  if (threadIdx.x == 0) {
    ws_ms[((size_t)b*16 + chunk)*2]     = M;
    ws_ms[((size_t)b*16 + chunk)*2 + 1] = ssum_c;
  }
}

// K2 v4: parallel combine. Grid (14 kchunks x 64 b), 1 thread = 1 output elem.
__global__ __launch_bounds__(256) void k_combine(const float* __restrict__ ws_ms,
                                                 const float* __restrict__ ws_ctx,
                                                 const float* __restrict__ hidden,
                                                 const float* __restrict__ emb_table,
                                                 const int* __restrict__ x,
                                                 unsigned short* __restrict__ rnnB) {
  const int b = blockIdx.y;
  const int k = blockIdx.x*256 + threadIdx.x;   // 0..3583
  unsigned short* rb = rnnB + (size_t)b*KTOT;

  if (k < TWOH) {
    float mc[16], sc[16];
#pragma unroll
    for (int c = 0; c < 16; ++c) {
      mc[c] = ws_ms[(b*16 + c)*2];
      sc[c] = ws_ms[(b*16 + c)*2 + 1];
    }
    float M = mc[0];
#pragma unroll
    for (int c = 1; c < 16; ++c) M = fmaxf(M, mc[c]);
    float wc[16], Ssum = 0.f;
#pragma unroll
    for (int c = 0; c < 16; ++c) { wc[c] = __expf(mc[c] - M); Ssum += wc[c]*sc[c]; }
    const float inv = 1.f / Ssum;
    float a = 0.f;
#pragma unroll
    for (int c = 0; c < 16; ++c) a += wc[c] * ws_ctx[((size_t)b*16 + c)*TWOH + k];
    rb[k] = f2bf(a * inv);
  } else if (k < KDIM) {
    const int xb = x[b];
    rb[k] = f2bf(emb_table[(size_t)xb*EMB + (k - TWOH)]);
  } else {
    rb[k] = f2bf(hidden[b*HDIM + (k - KDIM)]);
  }
}

// K3 v5 (R11 best): MFMA gate GEMM, k-loop unrolled x2.
__global__ __launch_bounds__(256) void k_gates(const unsigned short* __restrict__ rnnB,
                                               const float* __restrict__ W_ih,
                                               const float* __restrict__ W_hh,
                                               float* __restrict__ ws_gp) {
  const int lane = threadIdx.x & 63;
  const int wave = threadIdx.x >> 6;
  const int part = blockIdx.x & 7;     // k-part: 448 each
  const int rg   = blockIdx.x >> 3;    // 0..63
  const int row0 = rg*64 + wave*16;
  const int mlo  = lane & 15;
  const int kg   = lane >> 4;
  const int j    = row0 + mlo;

  f32x4 acc0 = {0.f,0.f,0.f,0.f}, acc1 = acc0, acc2 = acc0, acc3 = acc0;

  for (int k0 = 0; k0 < 448; k0 += 64) {
    const int kb0 = part*448 + k0;
    const int kb1 = kb0 + 32;          // 32-chunks never cross KDIM (all %32==0)
    const float* ws0 = (kb0 < KDIM) ? (W_ih + (size_t)j*KDIM + kb0 + kg*8)
                                    : (W_hh + (size_t)j*HDIM + (kb0 - KDIM) + kg*8);
    const float* ws1 = (kb1 < KDIM) ? (W_ih + (size_t)j*KDIM + kb1 + kg*8)
                                    : (W_hh + (size_t)j*HDIM + (kb1 - KDIM) + kg*8);
    const float4 wa0 = *reinterpret_cast<const float4*>(ws0);
    const float4 wb0 = *reinterpret_cast<const float4*>(ws0 + 4);
    const float4 wa1 = *reinterpret_cast<const float4*>(ws1);
    const float4 wb1 = *reinterpret_cast<const float4*>(ws1 + 4);

    const size_t ko0 = (size_t)kb0 + kg*8;
    const size_t ko1 = (size_t)kb1 + kg*8;
    const unsigned short* rp0 = rnnB + (size_t)mlo*KTOT;
    const bf16x8 b00 = *reinterpret_cast<const bf16x8*>(rp0 + ko0);
    const bf16x8 b10 = *reinterpret_cast<const bf16x8*>(rp0 + 16*KTOT + ko0);
    const bf16x8 b20 = *reinterpret_cast<const bf16x8*>(rp0 + 32*KTOT + ko0);
    const bf16x8 b30 = *reinterpret_cast<const bf16x8*>(rp0 + 48*KTOT + ko0);
    const bf16x8 b01 = *reinterpret_cast<const bf16x8*>(rp0 + ko1);
    const bf16x8 b11 = *reinterpret_cast<const bf16x8*>(rp0 + 16*KTOT + ko1);
    const bf16x8 b21 = *reinterpret_cast<const bf16x8*>(rp0 + 32*KTOT + ko1);
    const bf16x8 b31 = *reinterpret_cast<const bf16x8*>(rp0 + 48*KTOT + ko1);

    const bf16x8 af0 = cvt_frag(wa0, wb0);
    const bf16x8 af1 = cvt_frag(wa1, wb1);

    acc0 = __builtin_amdgcn_mfma_f32_16x16x32_bf16(af0, b00, acc0, 0, 0, 0);
    acc1 = __builtin_amdgcn_mfma_f32_16x16x32_bf16(af0, b10, acc1, 0, 0, 0);
    acc2 = __builtin_amdgcn_mfma_f32_16x16x32_bf16(af0, b20, acc2, 0, 0, 0);
    acc3 = __builtin_amdgcn_mfma_f32_16x16x32_bf16(af0, b30, acc3, 0, 0, 0);
    acc0 = __builtin_amdgcn_mfma_f32_16x16x32_bf16(af1, b01, acc0, 0, 0, 0);
    acc1 = __builtin_amdgcn_mfma_f32_16x16x32_bf16(af1, b11, acc1, 0, 0, 0);
    acc2 = __builtin_amdgcn_mfma_f32_16x16x32_bf16(af1, b21, acc2, 0, 0, 0);
    acc3 = __builtin_amdgcn_mfma_f32_16x16x32_bf16(af1, b31, acc3, 0, 0, 0);
  }

  const int mbase = row0 + kg*4;
#define G_ST(ACC, N)                                                          \
  {                                                                           \
    _Pragma("unroll")                                                         \
    for (int jj = 0; jj < 4; ++jj)                                            \
      ws_gp[((size_t)part*4096 + mbase + jj)*64 + ((N)*16 + mlo)] = ACC[jj];  \
  }
  G_ST(acc0, 0) G_ST(acc1, 1) G_ST(acc2, 2) G_ST(acc3, 3)
#undef G_ST
}

// K3b: sum 8 partials + biases, LSTM pointwise; emit h as f32 outs + bf16 hB.
__global__ __launch_bounds__(256) void k_lstm(const float* __restrict__ ws_gp,
                                              const float* __restrict__ b_ih,
                                              const float* __restrict__ b_hh,
                                              const float* __restrict__ cell,
                                              float* __restrict__ out_h,
                                              float* __restrict__ out_c,
                                              unsigned short* __restrict__ hB) {
  const int id = blockIdx.x*256 + threadIdx.x;  // 65536
  const int h = id >> 6, b = id & 63;
  float g[4];
#pragma unroll
  for (int gg = 0; gg < 4; ++gg) {
    const int j = gg*1024 + h;
    float v = b_ih[j] + b_hh[j];
#pragma unroll
    for (int p = 0; p < 8; ++p) v += ws_gp[((size_t)p*4096 + j)*64 + b];
    g[gg] = v;
  }
  const float iv = sigmoidf_(g[0]);
  const float fv = sigmoidf_(g[1]);
  const float gv = tanhf(g[2]);
  const float ov = sigmoidf_(g[3]);
  const float cold = cell[b*HDIM + h];
  const float cn = fmaf(fv, cold, iv*gv);
  const float hn = ov * tanhf(cn);
  out_h[b*HDIM + h] = hn;
  out_c[b*HDIM + h] = cn;
  hB[(size_t)b*HDIM + h] = f2bf(hn);
}

// K4 v10: MFMA fc GEMM, split-K=2. Grid 1000 = 500 row-blocks x 2 k-parts.
// part0 -> preds (no bias), part1 -> fpart (reuses dead ws_gp region).
__global__ __launch_bounds__(256) void k_fc(const unsigned short* __restrict__ hB,
                                            const float* __restrict__ fc_W,
                                            float* __restrict__ preds,
                                            float* __restrict__ fpart) {
  const int lane = threadIdx.x & 63;
  const int wave = threadIdx.x >> 6;
  const int rb   = blockIdx.x >> 1;            // 0..499
  const int part = blockIdx.x & 1;             // k-part: 512 each
  const int row0 = (rb*4 + wave)*16;           // 32000 rows
  const int mlo  = lane & 15;
  const int kg   = lane >> 4;

  const float* wrow = fc_W + (size_t)(row0 + mlo)*HDIM + part*512 + kg*8;
  const unsigned short* hp = hB + (size_t)mlo*HDIM + part*512 + kg*8;

  f32x4 acc0 = {0.f,0.f,0.f,0.f}, acc1 = acc0, acc2 = acc0, acc3 = acc0;

  for (int k0 = 0; k0 < 512; k0 += 64) {
    const float4 wa0 = *reinterpret_cast<const float4*>(wrow + k0);
    const float4 wb0 = *reinterpret_cast<const float4*>(wrow + k0 + 4);
    const float4 wa1 = *reinterpret_cast<const float4*>(wrow + k0 + 32);
    const float4 wb1 = *reinterpret_cast<const float4*>(wrow + k0 + 36);

    const bf16x8 b00 = *reinterpret_cast<const bf16x8*>(hp + k0);
    const bf16x8 b10 = *reinterpret_cast<const bf16x8*>(hp + 16*HDIM + k0);
    const bf16x8 b20 = *reinterpret_cast<const bf16x8*>(hp + 32*HDIM + k0);
    const bf16x8 b30 = *reinterpret_cast<const bf16x8*>(hp + 48*HDIM + k0);
    const bf16x8 b01 = *reinterpret_cast<const bf16x8*>(hp + k0 + 32);
    const bf16x8 b11 = *reinterpret_cast<const bf16x8*>(hp + 16*HDIM + k0 + 32);
    const bf16x8 b21 = *reinterpret_cast<const bf16x8*>(hp + 32*HDIM + k0 + 32);
    const bf16x8 b31 = *reinterpret_cast<const bf16x8*>(hp + 48*HDIM + k0 + 32);

    const bf16x8 af0 = cvt_frag(wa0, wb0);
    const bf16x8 af1 = cvt_frag(wa1, wb1);

    acc0 = __builtin_amdgcn_mfma_f32_16x16x32_bf16(af0, b00, acc0, 0, 0, 0);
    acc1 = __builtin_amdgcn_mfma_f32_16x16x32_bf16(af0, b10, acc1, 0, 0, 0);
    acc2 = __builtin_amdgcn_mfma_f32_16x16x32_bf16(af0, b20, acc2, 0, 0, 0);
    acc3 = __builtin_amdgcn_mfma_f32_16x16x32_bf16(af0, b30, acc3, 0, 0, 0);
    acc0 = __builtin_amdgcn_mfma_f32_16x16x32_bf16(af1, b01, acc0, 0, 0, 0);
    acc1 = __builtin_amdgcn_mfma_f32_16x16x32_bf16(af1, b11, acc1, 0, 0, 0);
    acc2 = __builtin_amdgcn_mfma_f32_16x16x32_bf16(af1, b21, acc2, 0, 0, 0);
    acc3 = __builtin_amdgcn_mfma_f32_16x16x32_bf16(af1, b31, acc3, 0, 0, 0);
  }

  float* dst = part ? fpart : preds;
  const int mbase = row0 + kg*4;
#define FC_STORE(ACC, N)                                                      \
  {                                                                           \
    float4 st = make_float4(ACC[0], ACC[1], ACC[2], ACC[3]);                  \
    *reinterpret_cast<float4*>(dst + (size_t)((N)*16 + mlo)*VOUT + mbase) = st; \
  }
  FC_STORE(acc0, 0) FC_STORE(acc1, 1) FC_STORE(acc2, 2) FC_STORE(acc3, 3)
#undef FC_STORE
}

// K4b: preds += fpart + bias (deterministic fixed-order).
__global__ __launch_bounds__(256) void k_fcred(float* __restrict__ preds,
                                               const float* __restrict__ fpart,
                                               const float* __restrict__ fc_b) {
  const size_t i4 = (size_t)blockIdx.x*256 + threadIdx.x;   // 512000 float4s
  const size_t idx = i4*4;
  const int r = (int)(idx % VOUT);
  const float4 p0 = *reinterpret_cast<const float4*>(preds + idx);
  const float4 p1 = *reinterpret_cast<const float4*>(fpart + idx);
  const float4 bb = *reinterpret_cast<const float4*>(fc_b + r);
  float4 st = make_float4(p0.x + p1.x + bb.x, p0.y + p1.y + bb.y,
                          p0.z + p1.z + bb.z, p0.w + p1.w + bb.w);
  *reinterpret_cast<float4*>(preds + idx) = st;
}

extern "C" void kernel_launch(void* const* d_in, const int* in_sizes, int n_in,
                              void* d_out, int out_size, void* d_ws, size_t ws_size,
                              hipStream_t stream) {
  const int*   x      = (const int*)  d_in[0];
  const float* enc    = (const float*)d_in[1];
  const float* hidden = (const float*)d_in[2];
  const float* cell   = (const float*)d_in[3];
  const float* embt   = (const float*)d_in[4];
  const float* eW     = (const float*)d_in[5];
  const float* eb     = (const float*)d_in[6];
  const float* W_ih   = (const float*)d_in[7];
  const float* W_hh   = (const float*)d_in[8];
  const float* b_ih   = (const float*)d_in[9];
  const float* b_hh   = (const float*)d_in[10];
  const float* fc_W   = (const float*)d_in[11];
  const float* fc_b   = (const float*)d_in[12];

  float* out   = (float*)d_out;
  float* preds = out;                              // 64*32000
  float* out_h = out + (size_t)BATCH*VOUT;         // 64*1024
  float* out_c = out_h + BATCH*HDIM;               // 64*1024
  float* ws    = (float*)d_ws;
  unsigned short* rnnB = (unsigned short*)(ws + WS_RNNB);
  unsigned short* hB   = (unsigned short*)(ws + WS_HB16);

  k_attn<<<dim3(16, 64), 256, 0, stream>>>(enc, eW, eb, hidden, ws + WS_MS, ws + WS_CTX);
  k_combine<<<dim3(14, 64), 256, 0, stream>>>(ws + WS_MS, ws + WS_CTX, hidden, embt, x, rnnB);
  k_gates<<<512, 256, 0, stream>>>(rnnB, W_ih, W_hh, ws + WS_GP);
  k_lstm<<<256, 256, 0, stream>>>(ws + WS_GP, b_ih, b_hh, cell, out_h, out_c, hB);
  k_fc<<<1000, 256, 0, stream>>>(hB, fc_W, preds, ws + WS_FP);
  k_fcred<<<2000, 256, 0, stream>>>(preds, ws + WS_FP, fc_b);
}

// Round 17
// 145.944 us; speedup vs baseline: 1.4870x; 1.0342x over previous
//
#include <hip/hip_runtime.h>

#define S_LEN 512
#define BATCH 64
#define HDIM  1024
#define TWOH  2048
#define EMB   512
#define KDIM  2560      // 2H + EMB
#define KTOT  3584      // 2H + EMB + H
#define VOUT  32000

// ws layout (float offsets)
#define WS_MS    64
#define WS_CTX   2112                        // f32 [64][16][2048] = 2,097,152 floats
#define WS_GP    WS_CTX                      // gate partials [8][4096][64] f32 — aliases dead ctx
#define WS_RNNB  (WS_CTX + 64*16*2048)       // bf16 [64][3584] = 114,688 floats
#define WS_HB16  (WS_RNNB + 114688)          // bf16 [64][1024] = 32,768 floats

typedef __attribute__((ext_vector_type(8))) short bf16x8;
typedef __attribute__((ext_vector_type(4))) float f32x4;

__device__ __forceinline__ float sigmoidf_(float x) { return 1.f/(1.f+__expf(-x)); }

// RNE float -> bf16 (finite inputs)
__device__ __forceinline__ unsigned short f2bf(float f) {
  union { float f; unsigned u; } v; v.f = f;
  return (unsigned short)((v.u + 0x7fffu + ((v.u >> 16) & 1u)) >> 16);
}

__device__ __forceinline__ bf16x8 cvt_frag(const float4& a, const float4& b) {
  bf16x8 r;
  r[0] = (short)f2bf(a.x); r[1] = (short)f2bf(a.y);
  r[2] = (short)f2bf(a.z); r[3] = (short)f2bf(a.w);
  r[4] = (short)f2bf(b.x); r[5] = (short)f2bf(b.y);
  r[6] = (short)f2bf(b.z); r[7] = (short)f2bf(b.w);
  return r;
}

// K1 v3: single-pass online-softmax context, row-pipelined, hb inline.
__global__ __launch_bounds__(256) void k_attn(const float* __restrict__ enc,
                                              const float* __restrict__ eW,
                                              const float* __restrict__ eb,
                                              const float* __restrict__ hidden,
                                              float* __restrict__ ws_ms,
                                              float* __restrict__ ws_ctx) {
  __shared__ float lds_ms[4][2];
  __shared__ float lds_ctx[4][2048];
  const int lane  = threadIdx.x & 63;
  const int wave  = threadIdx.x >> 6;
  const int chunk = blockIdx.x;   // 0..15
  const int b     = blockIdx.y;   // 0..63

  float hba = 0.f;
  for (int k = lane; k < HDIM; k += 64) hba += hidden[b*HDIM + k] * eW[k];
#pragma unroll
  for (int st = 32; st >= 1; st >>= 1) hba += __shfl_xor(hba, st, 64);
  const float hb = hba + eb[0];

  float4 w4[8];
#pragma unroll
  for (int k = 0; k < 8; ++k)
    w4[k] = *reinterpret_cast<const float4*>(eW + HDIM + 4*lane + 256*k);

  const int s0 = chunk*32 + wave*8;
  const float* base = enc + ((size_t)(s0*BATCH + b))*TWOH + 4*lane;

  float m = 0.f, ssum = 0.f;      // relu => e >= 0
  float4 ctx[8];
#pragma unroll
  for (int k = 0; k < 8; ++k) ctx[k] = make_float4(0.f, 0.f, 0.f, 0.f);

  float4 va[8], vb[8];
#pragma unroll
  for (int k = 0; k < 8; ++k) va[k] = *reinterpret_cast<const float4*>(base + 256*k);

#define ATTN_STEP(VCUR, VNXT, I)                                              \
  {                                                                           \
    if ((I) < 7) {                                                            \
      const float* pn = base + (size_t)((I)+1)*BATCH*TWOH;                    \
      _Pragma("unroll")                                                       \
      for (int k = 0; k < 8; ++k)                                             \
        VNXT[k] = *reinterpret_cast<const float4*>(pn + 256*k);               \
    }                                                                         \
    float a = 0.f;                                                            \
    _Pragma("unroll")                                                         \
    for (int k = 0; k < 8; ++k)                                               \
      a += VCUR[k].x*w4[k].x + VCUR[k].y*w4[k].y +                            \
           VCUR[k].z*w4[k].z + VCUR[k].w*w4[k].w;                             \
    _Pragma("unroll")                                                         \
    for (int st = 1; st < 64; st <<= 1) a += __shfl_xor(a, st, 64);           \
    const float e = fmaxf(a + hb, 0.f);                                       \
    if (e > m) {                                                              \
      const float sc = __expf(m - e);                                         \
      ssum = ssum*sc + 1.f;                                                   \
      _Pragma("unroll")                                                       \
      for (int k = 0; k < 8; ++k) {                                           \
        ctx[k].x = fmaf(ctx[k].x, sc, VCUR[k].x);                             \
        ctx[k].y = fmaf(ctx[k].y, sc, VCUR[k].y);                             \
        ctx[k].z = fmaf(ctx[k].z, sc, VCUR[k].z);                             \
        ctx[k].w = fmaf(ctx[k].w, sc, VCUR[k].w);                             \
      }                                                                       \
      m = e;                                                                  \
    } else {                                                                  \
      const float pw = __expf(e - m);                                         \
      ssum += pw;                                                             \
      _Pragma("unroll")                                                       \
      for (int k = 0; k < 8; ++k) {                                           \
        ctx[k].x = fmaf(pw, VCUR[k].x, ctx[k].x);                             \
        ctx[k].y = fmaf(pw, VCUR[k].y, ctx[k].y);                             \
        ctx[k].z = fmaf(pw, VCUR[k].z, ctx[k].z);                             \
        ctx[k].w = fmaf(pw, VCUR[k].w, ctx[k].w);                             \
      }                                                                       \
    }                                                                         \
  }

  ATTN_STEP(va, vb, 0)
  ATTN_STEP(vb, va, 1)
  ATTN_STEP(va, vb, 2)
  ATTN_STEP(vb, va, 3)
  ATTN_STEP(va, vb, 4)
  ATTN_STEP(vb, va, 5)
  ATTN_STEP(va, vb, 6)
  ATTN_STEP(vb, va, 7)
#undef ATTN_STEP

  if (lane == 0) { lds_ms[wave][0] = m; lds_ms[wave][1] = ssum; }
  __syncthreads();
  const float M = fmaxf(fmaxf(lds_ms[0][0], lds_ms[1][0]),
                        fmaxf(lds_ms[2][0], lds_ms[3][0]));
  const float wsc = __expf(m - M);
  float ssum_c = 0.f;
#pragma unroll
  for (int w = 0; w < 4; ++w) ssum_c += __expf(lds_ms[w][0] - M) * lds_ms[w][1];
#pragma unroll
  for (int k = 0; k < 8; ++k) {
    float4 c = ctx[k];
    c.x *= wsc; c.y *= wsc; c.z *= wsc; c.w *= wsc;
    *reinterpret_cast<float4*>(&lds_ctx[wave][4*lane + 256*k]) = c;
  }
  __syncthreads();
  float* outp = ws_ctx + ((size_t)b*16 + chunk)*TWOH;
  for (int d = threadIdx.x; d < TWOH; d += 256)
    outp[d] = lds_ctx[0][d] + lds_ctx[1][d] + lds_ctx[2][d] + lds_ctx[3][d];
  if (threadIdx.x == 0) {
    ws_ms[((size_t)b*16 + chunk)*2]     = M;
    ws_ms[((size_t)b*16 + chunk)*2 + 1] = ssum_c;
  }
}

// K2 v4: parallel combine. Grid (14 kchunks x 64 b), 1 thread = 1 output elem.
__global__ __launch_bounds__(256) void k_combine(const float* __restrict__ ws_ms,
                                                 const float* __restrict__ ws_ctx,
                                                 const float* __restrict__ hidden,
                                                 const float* __restrict__ emb_table,
                                                 const int* __restrict__ x,
                                                 unsigned short* __restrict__ rnnB) {
  const int b = blockIdx.y;
  const int k = blockIdx.x*256 + threadIdx.x;   // 0..3583
  unsigned short* rb = rnnB + (size_t)b*KTOT;

  if (k < TWOH) {
    float mc[16], sc[16];
#pragma unroll
    for (int c = 0; c < 16; ++c) {
      mc[c] = ws_ms[(b*16 + c)*2];
      sc[c] = ws_ms[(b*16 + c)*2 + 1];
    }
    float M = mc[0];
#pragma unroll
    for (int c = 1; c < 16; ++c) M = fmaxf(M, mc[c]);
    float wc[16], Ssum = 0.f;
#pragma unroll
    for (int c = 0; c < 16; ++c) { wc[c] = __expf(mc[c] - M); Ssum += wc[c]*sc[c]; }
    const float inv = 1.f / Ssum;
    float a = 0.f;
#pragma unroll
    for (int c = 0; c < 16; ++c) a += wc[c] * ws_ctx[((size_t)b*16 + c)*TWOH + k];
    rb[k] = f2bf(a * inv);
  } else if (k < KDIM) {
    const int xb = x[b];
    rb[k] = f2bf(emb_table[(size_t)xb*EMB + (k - TWOH)]);
  } else {
    rb[k] = f2bf(hidden[b*HDIM + (k - KDIM)]);
  }
}

// K3 v7: MFMA gate GEMM with explicit 2-deep register ping-pong (attn-style):
// issue step s+1's loads BEFORE computing step s. Arithmetic order = v5.
__global__ __launch_bounds__(256) void k_gates(const unsigned short* __restrict__ rnnB,
                                               const float* __restrict__ W_ih,
                                               const float* __restrict__ W_hh,
                                               float* __restrict__ ws_gp) {
  const int lane = threadIdx.x & 63;
  const int wave = threadIdx.x >> 6;
  const int part = blockIdx.x & 7;     // k-part: 448 each
  const int rg   = blockIdx.x >> 3;    // 0..63
  const int row0 = rg*64 + wave*16;
  const int mlo  = lane & 15;
  const int kg   = lane >> 4;
  const int j    = row0 + mlo;
  const unsigned short* rp0 = rnnB + (size_t)mlo*KTOT;

  f32x4 acc0 = {0.f,0.f,0.f,0.f}, acc1 = acc0, acc2 = acc0, acc3 = acc0;

  float4  Aa[4], Ab[4];
  bf16x8  Ba[8], Bb[8];

#define G_LOAD(AW, BB, S)                                                     \
  {                                                                           \
    const int kb0 = part*448 + (S)*64;                                        \
    const int kb1 = kb0 + 32;                                                 \
    const float* ws0 = (kb0 < KDIM) ? (W_ih + (size_t)j*KDIM + kb0 + kg*8)    \
                                    : (W_hh + (size_t)j*HDIM + (kb0-KDIM) + kg*8); \
    const float* ws1 = (kb1 < KDIM) ? (W_ih + (size_t)j*KDIM + kb1 + kg*8)    \
                                    : (W_hh + (size_t)j*HDIM + (kb1-KDIM) + kg*8); \
    AW[0] = *reinterpret_cast<const float4*>(ws0);                            \
    AW[1] = *reinterpret_cast<const float4*>(ws0 + 4);                        \
    AW[2] = *reinterpret_cast<const float4*>(ws1);                            \
    AW[3] = *reinterpret_cast<const float4*>(ws1 + 4);                        \
    const size_t ko0 = (size_t)kb0 + kg*8;                                    \
    const size_t ko1 = (size_t)kb1 + kg*8;                                    \
    BB[0] = *reinterpret_cast<const bf16x8*>(rp0 + ko0);                      \
    BB[1] = *reinterpret_cast<const bf16x8*>(rp0 + 16*KTOT + ko0);            \
    BB[2] = *reinterpret_cast<const bf16x8*>(rp0 + 32*KTOT + ko0);            \
    BB[3] = *reinterpret_cast<const bf16x8*>(rp0 + 48*KTOT + ko0);            \
    BB[4] = *reinterpret_cast<const bf16x8*>(rp0 + ko1);                      \
    BB[5] = *reinterpret_cast<const bf16x8*>(rp0 + 16*KTOT + ko1);            \
    BB[6] = *reinterpret_cast<const bf16x8*>(rp0 + 32*KTOT + ko1);            \
    BB[7] = *reinterpret_cast<const bf16x8*>(rp0 + 48*KTOT + ko1);            \
  }

#define G_COMP(AW, BB)                                                        \
  {                                                                           \
    const bf16x8 af0 = cvt_frag(AW[0], AW[1]);                                \
    const bf16x8 af1 = cvt_frag(AW[2], AW[3]);                                \
    acc0 = __builtin_amdgcn_mfma_f32_16x16x32_bf16(af0, BB[0], acc0, 0, 0, 0);\
    acc1 = __builtin_amdgcn_mfma_f32_16x16x32_bf16(af0, BB[1], acc1, 0, 0, 0);\
    acc2 = __builtin_amdgcn_mfma_f32_16x16x32_bf16(af0, BB[2], acc2, 0, 0, 0);\
    acc3 = __builtin_amdgcn_mfma_f32_16x16x32_bf16(af0, BB[3], acc3, 0, 0, 0);\
    acc0 = __builtin_amdgcn_mfma_f32_16x16x32_bf16(af1, BB[4], acc0, 0, 0, 0);\
    acc1 = __builtin_amdgcn_mfma_f32_16x16x32_bf16(af1, BB[5], acc1, 0, 0, 0);\
    acc2 = __builtin_amdgcn_mfma_f32_16x16x32_bf16(af1, BB[6], acc2, 0, 0, 0);\
    acc3 = __builtin_amdgcn_mfma_f32_16x16x32_bf16(af1, BB[7], acc3, 0, 0, 0);\
  }

  G_LOAD(Aa, Ba, 0)
  G_LOAD(Ab, Bb, 1) G_COMP(Aa, Ba)   // step 0 (prefetch 1)
  G_LOAD(Aa, Ba, 2) G_COMP(Ab, Bb)   // step 1 (prefetch 2)
  G_LOAD(Ab, Bb, 3) G_COMP(Aa, Ba)   // step 2
  G_LOAD(Aa, Ba, 4) G_COMP(Ab, Bb)   // step 3
  G_LOAD(Ab, Bb, 5) G_COMP(Aa, Ba)   // step 4
  G_LOAD(Aa, Ba, 6) G_COMP(Ab, Bb)   // step 5
  G_COMP(Aa, Ba)                      // step 6
#undef G_LOAD
#undef G_COMP

  const int mbase = row0 + kg*4;
#define G_ST(ACC, N)                                                          \
  {                                                                           \
    _Pragma("unroll")                                                         \
    for (int jj = 0; jj < 4; ++jj)                                            \
      ws_gp[((size_t)part*4096 + mbase + jj)*64 + ((N)*16 + mlo)] = ACC[jj];  \
  }
  G_ST(acc0, 0) G_ST(acc1, 1) G_ST(acc2, 2) G_ST(acc3, 3)
#undef G_ST
}

// K3b: sum 8 partials + biases, LSTM pointwise; emit h as f32 outs + bf16 hB.
__global__ __launch_bounds__(256) void k_lstm(const float* __restrict__ ws_gp,
                                              const float* __restrict__ b_ih,
                                              const float* __restrict__ b_hh,
                                              const float* __restrict__ cell,
                                              float* __restrict__ out_h,
                                              float* __restrict__ out_c,
                                              unsigned short* __restrict__ hB) {
  const int id = blockIdx.x*256 + threadIdx.x;  // 65536
  const int h = id >> 6, b = id & 63;
  float g[4];
#pragma unroll
  for (int gg = 0; gg < 4; ++gg) {
    const int j = gg*1024 + h;
    float v = b_ih[j] + b_hh[j];
#pragma unroll
    for (int p = 0; p < 8; ++p) v += ws_gp[((size_t)p*4096 + j)*64 + b];
    g[gg] = v;
  }
  const float iv = sigmoidf_(g[0]);
  const float fv = sigmoidf_(g[1]);
  const float gv = tanhf(g[2]);
  const float ov = sigmoidf_(g[3]);
  const float cold = cell[b*HDIM + h];
  const float cn = fmaf(fv, cold, iv*gv);
  const float hn = ov * tanhf(cn);
  out_h[b*HDIM + h] = hn;
  out_c[b*HDIM + h] = cn;
  hB[(size_t)b*HDIM + h] = f2bf(hn);
}

// K4 v11: MFMA fc GEMM with explicit 2-deep register ping-pong (attn-style).
// Arithmetic order = v8. Grid 500, 4 waves/block.
__global__ __launch_bounds__(256) void k_fc(const unsigned short* __restrict__ hB,
                                            const float* __restrict__ fc_W,
                                            const float* __restrict__ fc_b,
                                            float* __restrict__ preds) {
  const int lane = threadIdx.x & 63;
  const int wave = threadIdx.x >> 6;
  const int row0 = (blockIdx.x*4 + wave)*16;   // grid 500 -> 32000 rows
  const int mlo  = lane & 15;
  const int kg   = lane >> 4;

  const float* wrow = fc_W + (size_t)(row0 + mlo)*HDIM + kg*8;
  const unsigned short* hp = hB + (size_t)mlo*HDIM + kg*8;

  f32x4 acc0 = {0.f,0.f,0.f,0.f}, acc1 = acc0, acc2 = acc0, acc3 = acc0;

  float4  Aa[4], Ab[4];
  bf16x8  Ba[8], Bb[8];

#define FC_LOAD(AW, BB, K0)                                                   \
  {                                                                           \
    AW[0] = *reinterpret_cast<const float4*>(wrow + (K0));                    \
    AW[1] = *reinterpret_cast<const float4*>(wrow + (K0) + 4);                \
    AW[2] = *reinterpret_cast<const float4*>(wrow + (K0) + 32);               \
    AW[3] = *reinterpret_cast<const float4*>(wrow + (K0) + 36);               \
    BB[0] = *reinterpret_cast<const bf16x8*>(hp + (K0));                      \
    BB[1] = *reinterpret_cast<const bf16x8*>(hp + 16*HDIM + (K0));            \
    BB[2] = *reinterpret_cast<const bf16x8*>(hp + 32*HDIM + (K0));            \
    BB[3] = *reinterpret_cast<const bf16x8*>(hp + 48*HDIM + (K0));            \
    BB[4] = *reinterpret_cast<const bf16x8*>(hp + (K0) + 32);                 \
    BB[5] = *reinterpret_cast<const bf16x8*>(hp + 16*HDIM + (K0) + 32);       \
    BB[6] = *reinterpret_cast<const bf16x8*>(hp + 32*HDIM + (K0) + 32);       \
    BB[7] = *reinterpret_cast<const bf16x8*>(hp + 48*HDIM + (K0) + 32);       \
  }

#define FC_COMP(AW, BB)                                                       \
  {                                                                           \
    const bf16x8 af0 = cvt_frag(AW[0], AW[1]);                                \
    const bf16x8 af1 = cvt_frag(AW[2], AW[3]);                                \
    acc0 = __builtin_amdgcn_mfma_f32_16x16x32_bf16(af0, BB[0], acc0, 0, 0, 0);\
    acc1 = __builtin_amdgcn_mfma_f32_16x16x32_bf16(af0, BB[1], acc1, 0, 0, 0);\
    acc2 = __builtin_amdgcn_mfma_f32_16x16x32_bf16(af0, BB[2], acc2, 0, 0, 0);\
    acc3 = __builtin_amdgcn_mfma_f32_16x16x32_bf16(af0, BB[3], acc3, 0, 0, 0);\
    acc0 = __builtin_amdgcn_mfma_f32_16x16x32_bf16(af1, BB[4], acc0, 0, 0, 0);\
    acc1 = __builtin_amdgcn_mfma_f32_16x16x32_bf16(af1, BB[5], acc1, 0, 0, 0);\
    acc2 = __builtin_amdgcn_mfma_f32_16x16x32_bf16(af1, BB[6], acc2, 0, 0, 0);\
    acc3 = __builtin_amdgcn_mfma_f32_16x16x32_bf16(af1, BB[7], acc3, 0, 0, 0);\
  }

  FC_LOAD(Aa, Ba, 0)
  FC_LOAD(Ab, Bb, 64)  FC_COMP(Aa, Ba)
  FC_LOAD(Aa, Ba, 128) FC_COMP(Ab, Bb)
  FC_LOAD(Ab, Bb, 192) FC_COMP(Aa, Ba)
  FC_LOAD(Aa, Ba, 256) FC_COMP(Ab, Bb)
  FC_LOAD(Ab, Bb, 320) FC_COMP(Aa, Ba)
  FC_LOAD(Aa, Ba, 384) FC_COMP(Ab, Bb)
  FC_LOAD(Ab, Bb, 448) FC_COMP(Aa, Ba)
  FC_LOAD(Aa, Ba, 512) FC_COMP(Ab, Bb)
  FC_LOAD(Ab, Bb, 576) FC_COMP(Aa, Ba)
  FC_LOAD(Aa, Ba, 640) FC_COMP(Ab, Bb)
  FC_LOAD(Ab, Bb, 704) FC_COMP(Aa, Ba)
  FC_LOAD(Aa, Ba, 768) FC_COMP(Ab, Bb)
  FC_LOAD(Ab, Bb, 832) FC_COMP(Aa, Ba)
  FC_LOAD(Aa, Ba, 896) FC_COMP(Ab, Bb)
  FC_LOAD(Ab, Bb, 960) FC_COMP(Aa, Ba)
  FC_COMP(Ab, Bb)
#undef FC_LOAD
#undef FC_COMP

  const int mbase = row0 + kg*4;
  const float4 bias = make_float4(fc_b[mbase], fc_b[mbase+1],
                                  fc_b[mbase+2], fc_b[mbase+3]);
#define FC_STORE(ACC, N)                                                      \
  {                                                                           \
    float4 st = make_float4(ACC[0] + bias.x, ACC[1] + bias.y,                 \
                            ACC[2] + bias.z, ACC[3] + bias.w);                \
    *reinterpret_cast<float4*>(preds + (size_t)((N)*16 + mlo)*VOUT + mbase) = st; \
  }
  FC_STORE(acc0, 0) FC_STORE(acc1, 1) FC_STORE(acc2, 2) FC_STORE(acc3, 3)
#undef FC_STORE
}

extern "C" void kernel_launch(void* const* d_in, const int* in_sizes, int n_in,
                              void* d_out, int out_size, void* d_ws, size_t ws_size,
                              hipStream_t stream) {
  const int*   x      = (const int*)  d_in[0];
  const float* enc    = (const float*)d_in[1];
  const float* hidden = (const float*)d_in[2];
  const float* cell   = (const float*)d_in[3];
  const float* embt   = (const float*)d_in[4];
  const float* eW     = (const float*)d_in[5];
  const float* eb     = (const float*)d_in[6];
  const float* W_ih   = (const float*)d_in[7];
  const float* W_hh   = (const float*)d_in[8];
  const float* b_ih   = (const float*)d_in[9];
  const float* b_hh   = (const float*)d_in[10];
  const float* fc_W   = (const float*)d_in[11];
  const float* fc_b   = (const float*)d_in[12];

  float* out   = (float*)d_out;
  float* preds = out;                              // 64*32000
  float* out_h = out + (size_t)BATCH*VOUT;         // 64*1024
  float* out_c = out_h + BATCH*HDIM;               // 64*1024
  float* ws    = (float*)d_ws;
  unsigned short* rnnB = (unsigned short*)(ws + WS_RNNB);
  unsigned short* hB   = (unsigned short*)(ws + WS_HB16);

  k_attn<<<dim3(16, 64), 256, 0, stream>>>(enc, eW, eb, hidden, ws + WS_MS, ws + WS_CTX);
  k_combine<<<dim3(14, 64), 256, 0, stream>>>(ws + WS_MS, ws + WS_CTX, hidden, embt, x, rnnB);
  k_gates<<<512, 256, 0, stream>>>(rnnB, W_ih, W_hh, ws + WS_GP);
  k_lstm<<<256, 256, 0, stream>>>(ws + WS_GP, b_ih, b_hh, cell, out_h, out_c, hB);
  k_fc<<<500, 256, 0, stream>>>(hB, fc_W, fc_b, preds);
}

// Round 20
// 139.038 us; speedup vs baseline: 1.5609x; 1.0497x over previous
//
#include <hip/hip_runtime.h>

#define S_LEN 512
#define BATCH 64
#define HDIM  1024
#define TWOH  2048
#define EMB   512
#define KDIM  2560      // 2H + EMB
#define KTOT  3584      // 2H + EMB + H
#define VOUT  32000

// ws layout (float offsets)
#define WS_MS    64
#define WS_CTX   2112                        // f32 [64][16][2048] = 2,097,152 floats
#define WS_GP    WS_CTX                      // gate partials [8][4096][64] f32 — aliases dead ctx
#define WS_RNNB  (WS_CTX + 64*16*2048)       // bf16 [64][3584] = 114,688 floats
#define WS_HB16  (WS_RNNB + 114688)          // bf16 [64][1024] = 32,768 floats

typedef __attribute__((ext_vector_type(8))) short bf16x8;
typedef __attribute__((ext_vector_type(4))) float f32x4;

__device__ __forceinline__ float sigmoidf_(float x) { return 1.f/(1.f+__expf(-x)); }

// RNE float -> bf16 (finite inputs)
__device__ __forceinline__ unsigned short f2bf(float f) {
  union { float f; unsigned u; } v; v.f = f;
  return (unsigned short)((v.u + 0x7fffu + ((v.u >> 16) & 1u)) >> 16);
}

__device__ __forceinline__ bf16x8 cvt_frag(const float4& a, const float4& b) {
  bf16x8 r;
  r[0] = (short)f2bf(a.x); r[1] = (short)f2bf(a.y);
  r[2] = (short)f2bf(a.z); r[3] = (short)f2bf(a.w);
  r[4] = (short)f2bf(b.x); r[5] = (short)f2bf(b.y);
  r[6] = (short)f2bf(b.z); r[7] = (short)f2bf(b.w);
  return r;
}

// K1 v3: single-pass online-softmax context, row-pipelined, hb inline.
__global__ __launch_bounds__(256) void k_attn(const float* __restrict__ enc,
                                              const float* __restrict__ eW,
                                              const float* __restrict__ eb,
                                              const float* __restrict__ hidden,
                                              float* __restrict__ ws_ms,
                                              float* __restrict__ ws_ctx) {
  __shared__ float lds_ms[4][2];
  __shared__ float lds_ctx[4][2048];
  const int lane  = threadIdx.x & 63;
  const int wave  = threadIdx.x >> 6;
  const int chunk = blockIdx.x;   // 0..15
  const int b     = blockIdx.y;   // 0..63

  float hba = 0.f;
  for (int k = lane; k < HDIM; k += 64) hba += hidden[b*HDIM + k] * eW[k];
#pragma unroll
  for (int st = 32; st >= 1; st >>= 1) hba += __shfl_xor(hba, st, 64);
  const float hb = hba + eb[0];

  float4 w4[8];
#pragma unroll
  for (int k = 0; k < 8; ++k)
    w4[k] = *reinterpret_cast<const float4*>(eW + HDIM + 4*lane + 256*k);

  const int s0 = chunk*32 + wave*8;
  const float* base = enc + ((size_t)(s0*BATCH + b))*TWOH + 4*lane;

  float m = 0.f, ssum = 0.f;      // relu => e >= 0
  float4 ctx[8];
#pragma unroll
  for (int k = 0; k < 8; ++k) ctx[k] = make_float4(0.f, 0.f, 0.f, 0.f);

  float4 va[8], vb[8];
#pragma unroll
  for (int k = 0; k < 8; ++k) va[k] = *reinterpret_cast<const float4*>(base + 256*k);

#define ATTN_STEP(VCUR, VNXT, I)                                              \
  {                                                                           \
    if ((I) < 7) {                                                            \
      const float* pn = base + (size_t)((I)+1)*BATCH*TWOH;                    \
      _Pragma("unroll")                                                       \
      for (int k = 0; k < 8; ++k)                                             \
        VNXT[k] = *reinterpret_cast<const float4*>(pn + 256*k);               \
    }                                                                         \
    float a = 0.f;                                                            \
    _Pragma("unroll")                                                         \
    for (int k = 0; k < 8; ++k)                                               \
      a += VCUR[k].x*w4[k].x + VCUR[k].y*w4[k].y +                            \
           VCUR[k].z*w4[k].z + VCUR[k].w*w4[k].w;                             \
    _Pragma("unroll")                                                         \
    for (int st = 1; st < 64; st <<= 1) a += __shfl_xor(a, st, 64);           \
    const float e = fmaxf(a + hb, 0.f);                                       \
    if (e > m) {                                                              \
      const float sc = __expf(m - e);                                         \
      ssum = ssum*sc + 1.f;                                                   \
      _Pragma("unroll")                                                       \
      for (int k = 0; k < 8; ++k) {                                           \
        ctx[k].x = fmaf(ctx[k].x, sc, VCUR[k].x);                             \
        ctx[k].y = fmaf(ctx[k].y, sc, VCUR[k].y);                             \
        ctx[k].z = fmaf(ctx[k].z, sc, VCUR[k].z);                             \
        ctx[k].w = fmaf(ctx[k].w, sc, VCUR[k].w);                             \
      }                                                                       \
      m = e;                                                                  \
    } else {                                                                  \
      const float pw = __expf(e - m);                                         \
      ssum += pw;                                                             \
      _Pragma("unroll")                                                       \
      for (int k = 0; k < 8; ++k) {                                           \
        ctx[k].x = fmaf(pw, VCUR[k].x, ctx[k].x);                             \
        ctx[k].y = fmaf(pw, VCUR[k].y, ctx[k].y);                             \
        ctx[k].z = fmaf(pw, VCUR[k].z, ctx[k].z);                             \
        ctx[k].w = fmaf(pw, VCUR[k].w, ctx[k].w);                             \
      }                                                                       \
    }                                                                         \
  }

  ATTN_STEP(va, vb, 0)
  ATTN_STEP(vb, va, 1)
  ATTN_STEP(va, vb, 2)
  ATTN_STEP(vb, va, 3)
  ATTN_STEP(va, vb, 4)
  ATTN_STEP(vb, va, 5)
  ATTN_STEP(va, vb, 6)
  ATTN_STEP(vb, va, 7)
#undef ATTN_STEP

  if (lane == 0) { lds_ms[wave][0] = m; lds_ms[wave][1] = ssum; }
  __syncthreads();
  const float M = fmaxf(fmaxf(lds_ms[0][0], lds_ms[1][0]),
                        fmaxf(lds_ms[2][0], lds_ms[3][0]));
  const float wsc = __expf(m - M);
  float ssum_c = 0.f;
#pragma unroll
  for (int w = 0; w < 4; ++w) ssum_c += __expf(lds_ms[w][0] - M) * lds_ms[w][1];
#pragma unroll
  for (int k = 0; k < 8; ++k) {
    float4 c = ctx[k];
    c.x *= wsc; c.y *= wsc; c.z *= wsc; c.w *= wsc;
    *reinterpret_cast<float4*>(&lds_ctx[wave][4*lane + 256*k]) = c;
  }
  __syncthreads();
  float* outp = ws_ctx + ((size_t)b*16 + chunk)*TWOH;
  for (int d = threadIdx.x; d < TWOH; d += 256)
    outp[d] = lds_ctx[0][d] + lds_ctx[1][d] + lds_ctx[2][d] + lds_ctx[3][d];
  if (threadIdx.x == 0) {
    ws_ms[((size_t)b*16 + chunk)*2]     = M;
    ws_ms[((size_t)b*16 + chunk)*2 + 1] = ssum_c;
  }
}

// K2 v4: parallel combine. Grid (14 kchunks x 64 b), 1 thread = 1 output elem.
__global__ __launch_bounds__(256) void k_combine(const float* __restrict__ ws_ms,
                                                 const float* __restrict__ ws_ctx,
                                                 const float* __restrict__ hidden,
                                                 const float* __restrict__ emb_table,
                                                 const int* __restrict__ x,
                                                 unsigned short* __restrict__ rnnB) {
  const int b = blockIdx.y;
  const int k = blockIdx.x*256 + threadIdx.x;   // 0..3583
  unsigned short* rb = rnnB + (size_t)b*KTOT;

  if (k < TWOH) {
    float mc[16], sc[16];
#pragma unroll
    for (int c = 0; c < 16; ++c) {
      mc[c] = ws_ms[(b*16 + c)*2];
      sc[c] = ws_ms[(b*16 + c)*2 + 1];
    }
    float M = mc[0];
#pragma unroll
    for (int c = 1; c < 16; ++c) M = fmaxf(M, mc[c]);
    float wc[16], Ssum = 0.f;
#pragma unroll
    for (int c = 0; c < 16; ++c) { wc[c] = __expf(mc[c] - M); Ssum += wc[c]*sc[c]; }
    const float inv = 1.f / Ssum;
    float a = 0.f;
#pragma unroll
    for (int c = 0; c < 16; ++c) a += wc[c] * ws_ctx[((size_t)b*16 + c)*TWOH + k];
    rb[k] = f2bf(a * inv);
  } else if (k < KDIM) {
    const int xb = x[b];
    rb[k] = f2bf(emb_table[(size_t)xb*EMB + (k - TWOH)]);
  } else {
    rb[k] = f2bf(hidden[b*HDIM + (k - KDIM)]);
  }
}

// K3 v7: MFMA gate GEMM with explicit 2-deep register ping-pong (control —
// unchanged from R17).
__global__ __launch_bounds__(256) void k_gates(const unsigned short* __restrict__ rnnB,
                                               const float* __restrict__ W_ih,
                                               const float* __restrict__ W_hh,
                                               float* __restrict__ ws_gp) {
  const int lane = threadIdx.x & 63;
  const int wave = threadIdx.x >> 6;
  const int part = blockIdx.x & 7;     // k-part: 448 each
  const int rg   = blockIdx.x >> 3;    // 0..63
  const int row0 = rg*64 + wave*16;
  const int mlo  = lane & 15;
  const int kg   = lane >> 4;
  const int j    = row0 + mlo;
  const unsigned short* rp0 = rnnB + (size_t)mlo*KTOT;

  f32x4 acc0 = {0.f,0.f,0.f,0.f}, acc1 = acc0, acc2 = acc0, acc3 = acc0;

  float4  Aa[4], Ab[4];
  bf16x8  Ba[8], Bb[8];

#define G_LOAD(AW, BB, S)                                                     \
  {                                                                           \
    const int kb0 = part*448 + (S)*64;                                        \
    const int kb1 = kb0 + 32;                                                 \
    const float* ws0 = (kb0 < KDIM) ? (W_ih + (size_t)j*KDIM + kb0 + kg*8)    \
                                    : (W_hh + (size_t)j*HDIM + (kb0-KDIM) + kg*8); \
    const float* ws1 = (kb1 < KDIM) ? (W_ih + (size_t)j*KDIM + kb1 + kg*8)    \
                                    : (W_hh + (size_t)j*HDIM + (kb1-KDIM) + kg*8); \
    AW[0] = *reinterpret_cast<const float4*>(ws0);                            \
    AW[1] = *reinterpret_cast<const float4*>(ws0 + 4);                        \
    AW[2] = *reinterpret_cast<const float4*>(ws1);                            \
    AW[3] = *reinterpret_cast<const float4*>(ws1 + 4);                        \
    const size_t ko0 = (size_t)kb0 + kg*8;                                    \
    const size_t ko1 = (size_t)kb1 + kg*8;                                    \
    BB[0] = *reinterpret_cast<const bf16x8*>(rp0 + ko0);                      \
    BB[1] = *reinterpret_cast<const bf16x8*>(rp0 + 16*KTOT + ko0);            \
    BB[2] = *reinterpret_cast<const bf16x8*>(rp0 + 32*KTOT + ko0);            \
    BB[3] = *reinterpret_cast<const bf16x8*>(rp0 + 48*KTOT + ko0);            \
    BB[4] = *reinterpret_cast<const bf16x8*>(rp0 + ko1);                      \
    BB[5] = *reinterpret_cast<const bf16x8*>(rp0 + 16*KTOT + ko1);            \
    BB[6] = *reinterpret_cast<const bf16x8*>(rp0 + 32*KTOT + ko1);            \
    BB[7] = *reinterpret_cast<const bf16x8*>(rp0 + 48*KTOT + ko1);            \
  }

#define G_COMP(AW, BB)                                                        \
  {                                                                           \
    const bf16x8 af0 = cvt_frag(AW[0], AW[1]);                                \
    const bf16x8 af1 = cvt_frag(AW[2], AW[3]);                                \
    acc0 = __builtin_amdgcn_mfma_f32_16x16x32_bf16(af0, BB[0], acc0, 0, 0, 0);\
    acc1 = __builtin_amdgcn_mfma_f32_16x16x32_bf16(af0, BB[1], acc1, 0, 0, 0);\
    acc2 = __builtin_amdgcn_mfma_f32_16x16x32_bf16(af0, BB[2], acc2, 0, 0, 0);\
    acc3 = __builtin_amdgcn_mfma_f32_16x16x32_bf16(af0, BB[3], acc3, 0, 0, 0);\
    acc0 = __builtin_amdgcn_mfma_f32_16x16x32_bf16(af1, BB[4], acc0, 0, 0, 0);\
    acc1 = __builtin_amdgcn_mfma_f32_16x16x32_bf16(af1, BB[5], acc1, 0, 0, 0);\
    acc2 = __builtin_amdgcn_mfma_f32_16x16x32_bf16(af1, BB[6], acc2, 0, 0, 0);\
    acc3 = __builtin_amdgcn_mfma_f32_16x16x32_bf16(af1, BB[7], acc3, 0, 0, 0);\
  }

  G_LOAD(Aa, Ba, 0)
  G_LOAD(Ab, Bb, 1) G_COMP(Aa, Ba)
  G_LOAD(Aa, Ba, 2) G_COMP(Ab, Bb)
  G_LOAD(Ab, Bb, 3) G_COMP(Aa, Ba)
  G_LOAD(Aa, Ba, 4) G_COMP(Ab, Bb)
  G_LOAD(Ab, Bb, 5) G_COMP(Aa, Ba)
  G_LOAD(Aa, Ba, 6) G_COMP(Ab, Bb)
  G_COMP(Aa, Ba)
#undef G_LOAD
#undef G_COMP

  const int mbase = row0 + kg*4;
#define G_ST(ACC, N)                                                          \
  {                                                                           \
    _Pragma("unroll")                                                         \
    for (int jj = 0; jj < 4; ++jj)                                            \
      ws_gp[((size_t)part*4096 + mbase + jj)*64 + ((N)*16 + mlo)] = ACC[jj];  \
  }
  G_ST(acc0, 0) G_ST(acc1, 1) G_ST(acc2, 2) G_ST(acc3, 3)
#undef G_ST
}

// K3b: sum 8 partials + biases, LSTM pointwise; emit h as f32 outs + bf16 hB.
__global__ __launch_bounds__(256) void k_lstm(const float* __restrict__ ws_gp,
                                              const float* __restrict__ b_ih,
                                              const float* __restrict__ b_hh,
                                              const float* __restrict__ cell,
                                              float* __restrict__ out_h,
                                              float* __restrict__ out_c,
                                              unsigned short* __restrict__ hB) {
  const int id = blockIdx.x*256 + threadIdx.x;  // 65536
  const int h = id >> 6, b = id & 63;
  float g[4];
#pragma unroll
  for (int gg = 0; gg < 4; ++gg) {
    const int j = gg*1024 + h;
    float v = b_ih[j] + b_hh[j];
#pragma unroll
    for (int p = 0; p < 8; ++p) v += ws_gp[((size_t)p*4096 + j)*64 + b];
    g[gg] = v;
  }
  const float iv = sigmoidf_(g[0]);
  const float fv = sigmoidf_(g[1]);
  const float gv = tanhf(g[2]);
  const float ov = sigmoidf_(g[3]);
  const float cold = cell[b*HDIM + h];
  const float cn = fmaf(fv, cold, iv*gv);
  const float hn = ov * tanhf(cn);
  out_h[b*HDIM + h] = hn;
  out_c[b*HDIM + h] = cn;
  hB[(size_t)b*HDIM + h] = f2bf(hn);
}

// K4 v12: LDS-staged MFMA fc GEMM. Block = 64 rows x 64 batch, 4 waves.
// Per 64-k chunk: cooperative ROW-CONTIGUOUS global load of the 16KB A-tile
// (wave instr = 4 rows x 256B dense), f2bf in regs, store to XOR-swizzled
// double-buffered LDS bf16 tile [64][64] (byte ^= (row&7)<<4 fixes the
// 128B-row-stride 16-way ds_read conflict), ds_read_b128 fragments, MFMA.
// Arithmetic identical to v8/v11 (same f2bf, same k order) -> same absmax.
__global__ __launch_bounds__(256) void k_fc(const unsigned short* __restrict__ hB,
                                            const float* __restrict__ fc_W,
                                            const float* __restrict__ fc_b,
                                            float* __restrict__ preds) {
  __shared__ unsigned short lds_a[2][64*64];   // 2 x 8KB
  const int tid  = threadIdx.x;
  const int lane = tid & 63;
  const int wave = tid >> 6;
  const int row0b = blockIdx.x * 64;           // grid 500 -> 32000 rows
  const int mlo  = lane & 15;
  const int kg   = lane >> 4;
  const int srow = tid >> 4;                   // staging row 0..15 (+j*16)
  const int scol = (tid & 15) * 4;             // staging col (floats)

  const unsigned short* hp = hB + (size_t)mlo*HDIM + kg*8;

  f32x4 acc0 = {0.f,0.f,0.f,0.f}, acc1 = acc0, acc2 = acc0, acc3 = acc0;
  float4 st[4];

#define FC_GLOAD(C)                                                           \
  _Pragma("unroll")                                                           \
  for (int jj = 0; jj < 4; ++jj)                                              \
    st[jj] = *reinterpret_cast<const float4*>(                                \
        fc_W + (size_t)(row0b + srow + jj*16)*HDIM + (C)*64 + scol);

#define FC_SWRITE(BUF)                                                        \
  _Pragma("unroll")                                                           \
  for (int jj = 0; jj < 4; ++jj) {                                            \
    const int r = srow + jj*16;                                               \
    unsigned short tmp[4];                                                    \
    tmp[0] = f2bf(st[jj].x); tmp[1] = f2bf(st[jj].y);                         \
    tmp[2] = f2bf(st[jj].z); tmp[3] = f2bf(st[jj].w);                         \
    const int boff = r*128 + ((scol*2) ^ ((r & 7) << 4));                     \
    *reinterpret_cast<uint2*>(reinterpret_cast<char*>(lds_a[BUF]) + boff) =   \
        *reinterpret_cast<const uint2*>(tmp);                                 \
  }

  FC_GLOAD(0)
  FC_SWRITE(0)
  __syncthreads();

  int cur = 0;
  const int arow = wave*16 + mlo;
  const int abase = arow*128;
  const int asw  = (arow & 7) << 4;

  for (int c = 0; c < 16; ++c) {
    if (c < 15) FC_GLOAD(c+1)

    const bf16x8 af0 = *reinterpret_cast<const bf16x8*>(
        reinterpret_cast<const char*>(lds_a[cur]) + abase + ((kg*16) ^ asw));
    const bf16x8 af1 = *reinterpret_cast<const bf16x8*>(
        reinterpret_cast<const char*>(lds_a[cur]) + abase + ((64 + kg*16) ^ asw));

    const int K0 = c*64;
    const bf16x8 b00 = *reinterpret_cast<const bf16x8*>(hp + K0);
    const bf16x8 b10 = *reinterpret_cast<const bf16x8*>(hp + 16*HDIM + K0);
    const bf16x8 b20 = *reinterpret_cast<const bf16x8*>(hp + 32*HDIM + K0);
    const bf16x8 b30 = *reinterpret_cast<const bf16x8*>(hp + 48*HDIM + K0);
    const bf16x8 b01 = *reinterpret_cast<const bf16x8*>(hp + K0 + 32);
    const bf16x8 b11 = *reinterpret_cast<const bf16x8*>(hp + 16*HDIM + K0 + 32);
    const bf16x8 b21 = *reinterpret_cast<const bf16x8*>(hp + 32*HDIM + K0 + 32);
    const bf16x8 b31 = *reinterpret_cast<const bf16x8*>(hp + 48*HDIM + K0 + 32);

    acc0 = __builtin_amdgcn_mfma_f32_16x16x32_bf16(af0, b00, acc0, 0, 0, 0);
    acc1 = __builtin_amdgcn_mfma_f32_16x16x32_bf16(af0, b10, acc1, 0, 0, 0);
    acc2 = __builtin_amdgcn_mfma_f32_16x16x32_bf16(af0, b20, acc2, 0, 0, 0);
    acc3 = __builtin_amdgcn_mfma_f32_16x16x32_bf16(af0, b30, acc3, 0, 0, 0);
    acc0 = __builtin_amdgcn_mfma_f32_16x16x32_bf16(af1, b01, acc0, 0, 0, 0);
    acc1 = __builtin_amdgcn_mfma_f32_16x16x32_bf16(af1, b11, acc1, 0, 0, 0);
    acc2 = __builtin_amdgcn_mfma_f32_16x16x32_bf16(af1, b21, acc2, 0, 0, 0);
    acc3 = __builtin_amdgcn_mfma_f32_16x16x32_bf16(af1, b31, acc3, 0, 0, 0);

    if (c < 15) FC_SWRITE(cur ^ 1)
    __syncthreads();
    cur ^= 1;
  }
#undef FC_GLOAD
#undef FC_SWRITE

  const int mbase = row0b + wave*16 + kg*4;
  const float4 bias = make_float4(fc_b[mbase], fc_b[mbase+1],
                                  fc_b[mbase+2], fc_b[mbase+3]);
#define FC_STORE(ACC, N)                                                      \
  {                                                                           \
    float4 stv = make_float4(ACC[0] + bias.x, ACC[1] + bias.y,                \
                             ACC[2] + bias.z, ACC[3] + bias.w);               \
    *reinterpret_cast<float4*>(preds + (size_t)((N)*16 + mlo)*VOUT + mbase) = stv; \
  }
  FC_STORE(acc0, 0) FC_STORE(acc1, 1) FC_STORE(acc2, 2) FC_STORE(acc3, 3)
#undef FC_STORE
}

extern "C" void kernel_launch(void* const* d_in, const int* in_sizes, int n_in,
                              void* d_out, int out_size, void* d_ws, size_t ws_size,
                              hipStream_t stream) {
  const int*   x      = (const int*)  d_in[0];
  const float* enc    = (const float*)d_in[1];
  const float* hidden = (const float*)d_in[2];
  const float* cell   = (const float*)d_in[3];
  const float* embt   = (const float*)d_in[4];
  const float* eW     = (const float*)d_in[5];
  const float* eb     = (const float*)d_in[6];
  const float* W_ih   = (const float*)d_in[7];
  const float* W_hh   = (const float*)d_in[8];
  const float* b_ih   = (const float*)d_in[9];
  const float* b_hh   = (const float*)d_in[10];
  const float* fc_W   = (const float*)d_in[11];
  const float* fc_b   = (const float*)d_in[12];

  float* out   = (float*)d_out;
  float* preds = out;                              // 64*32000
  float* out_h = out + (size_t)BATCH*VOUT;         // 64*1024
  float* out_c = out_h + BATCH*HDIM;               // 64*1024
  float* ws    = (float*)d_ws;
  unsigned short* rnnB = (unsigned short*)(ws + WS_RNNB);
  unsigned short* hB   = (unsigned short*)(ws + WS_HB16);

  k_attn<<<dim3(16, 64), 256, 0, stream>>>(enc, eW, eb, hidden, ws + WS_MS, ws + WS_CTX);
  k_combine<<<dim3(14, 64), 256, 0, stream>>>(ws + WS_MS, ws + WS_CTX, hidden, embt, x, rnnB);
  k_gates<<<512, 256, 0, stream>>>(rnnB, W_ih, W_hh, ws + WS_GP);
  k_lstm<<<256, 256, 0, stream>>>(ws + WS_GP, b_ih, b_hh, cell, out_h, out_c, hB);
  k_fc<<<500, 256, 0, stream>>>(hB, fc_W, fc_b, preds);
}

// Round 21
// 137.107 us; speedup vs baseline: 1.5829x; 1.0141x over previous
//
#include <hip/hip_runtime.h>

#define S_LEN 512
#define BATCH 64
#define HDIM  1024
#define TWOH  2048
#define EMB   512
#define KDIM  2560      // 2H + EMB
#define KTOT  3584      // 2H + EMB + H
#define VOUT  32000

// ws layout (float offsets)
#define WS_MS    64
#define WS_CTX   2112                        // f32 [64][16][2048] = 2,097,152 floats
#define WS_GP    WS_CTX                      // gate partials [8][4096][64] f32 — aliases dead ctx
#define WS_RNNB  (WS_CTX + 64*16*2048)       // bf16 [64][3584] = 114,688 floats
#define WS_HB16  (WS_RNNB + 114688)          // bf16 [64][1024] = 32,768 floats

typedef __attribute__((ext_vector_type(8))) short bf16x8;
typedef __attribute__((ext_vector_type(4))) float f32x4;

__device__ __forceinline__ float sigmoidf_(float x) { return 1.f/(1.f+__expf(-x)); }

// RNE float -> bf16 (finite inputs)
__device__ __forceinline__ unsigned short f2bf(float f) {
  union { float f; unsigned u; } v; v.f = f;
  return (unsigned short)((v.u + 0x7fffu + ((v.u >> 16) & 1u)) >> 16);
}

// K1 v3: single-pass online-softmax context, row-pipelined, hb inline.
__global__ __launch_bounds__(256) void k_attn(const float* __restrict__ enc,
                                              const float* __restrict__ eW,
                                              const float* __restrict__ eb,
                                              const float* __restrict__ hidden,
                                              float* __restrict__ ws_ms,
                                              float* __restrict__ ws_ctx) {
  __shared__ float lds_ms[4][2];
  __shared__ float lds_ctx[4][2048];
  const int lane  = threadIdx.x & 63;
  const int wave  = threadIdx.x >> 6;
  const int chunk = blockIdx.x;   // 0..15
  const int b     = blockIdx.y;   // 0..63

  float hba = 0.f;
  for (int k = lane; k < HDIM; k += 64) hba += hidden[b*HDIM + k] * eW[k];
#pragma unroll
  for (int st = 32; st >= 1; st >>= 1) hba += __shfl_xor(hba, st, 64);
  const float hb = hba + eb[0];

  float4 w4[8];
#pragma unroll
  for (int k = 0; k < 8; ++k)
    w4[k] = *reinterpret_cast<const float4*>(eW + HDIM + 4*lane + 256*k);

  const int s0 = chunk*32 + wave*8;
  const float* base = enc + ((size_t)(s0*BATCH + b))*TWOH + 4*lane;

  float m = 0.f, ssum = 0.f;      // relu => e >= 0
  float4 ctx[8];
#pragma unroll
  for (int k = 0; k < 8; ++k) ctx[k] = make_float4(0.f, 0.f, 0.f, 0.f);

  float4 va[8], vb[8];
#pragma unroll
  for (int k = 0; k < 8; ++k) va[k] = *reinterpret_cast<const float4*>(base + 256*k);

#define ATTN_STEP(VCUR, VNXT, I)                                              \
  {                                                                           \
    if ((I) < 7) {                                                            \
      const float* pn = base + (size_t)((I)+1)*BATCH*TWOH;                    \
      _Pragma("unroll")                                                       \
      for (int k = 0; k < 8; ++k)                                             \
        VNXT[k] = *reinterpret_cast<const float4*>(pn + 256*k);               \
    }                                                                         \
    float a = 0.f;                                                            \
    _Pragma("unroll")                                                         \
    for (int k = 0; k < 8; ++k)                                               \
      a += VCUR[k].x*w4[k].x + VCUR[k].y*w4[k].y +                            \
           VCUR[k].z*w4[k].z + VCUR[k].w*w4[k].w;                             \
    _Pragma("unroll")                                                         \
    for (int st = 1; st < 64; st <<= 1) a += __shfl_xor(a, st, 64);           \
    const float e = fmaxf(a + hb, 0.f);                                       \
    if (e > m) {                                                              \
      const float sc = __expf(m - e);                                         \
      ssum = ssum*sc + 1.f;                                                   \
      _Pragma("unroll")                                                       \
      for (int k = 0; k < 8; ++k) {                                           \
        ctx[k].x = fmaf(ctx[k].x, sc, VCUR[k].x);                             \
        ctx[k].y = fmaf(ctx[k].y, sc, VCUR[k].y);                             \
        ctx[k].z = fmaf(ctx[k].z, sc, VCUR[k].z);                             \
        ctx[k].w = fmaf(ctx[k].w, sc, VCUR[k].w);                             \
      }                                                                       \
      m = e;                                                                  \
    } else {                                                                  \
      const float pw = __expf(e - m);                                         \
      ssum += pw;                                                             \
      _Pragma("unroll")                                                       \
      for (int k = 0; k < 8; ++k) {                                           \
        ctx[k].x = fmaf(pw, VCUR[k].x, ctx[k].x);                             \
        ctx[k].y = fmaf(pw, VCUR[k].y, ctx[k].y);                             \
        ctx[k].z = fmaf(pw, VCUR[k].z, ctx[k].z);                             \
        ctx[k].w = fmaf(pw, VCUR[k].w, ctx[k].w);                             \
      }                                                                       \
    }                                                                         \
  }

  ATTN_STEP(va, vb, 0)
  ATTN_STEP(vb, va, 1)
  ATTN_STEP(va, vb, 2)
  ATTN_STEP(vb, va, 3)
  ATTN_STEP(va, vb, 4)
  ATTN_STEP(vb, va, 5)
  ATTN_STEP(va, vb, 6)
  ATTN_STEP(vb, va, 7)
#undef ATTN_STEP

  if (lane == 0) { lds_ms[wave][0] = m; lds_ms[wave][1] = ssum; }
  __syncthreads();
  const float M = fmaxf(fmaxf(lds_ms[0][0], lds_ms[1][0]),
                        fmaxf(lds_ms[2][0], lds_ms[3][0]));
  const float wsc = __expf(m - M);
  float ssum_c = 0.f;
#pragma unroll
  for (int w = 0; w < 4; ++w) ssum_c += __expf(lds_ms[w][0] - M) * lds_ms[w][1];
#pragma unroll
  for (int k = 0; k < 8; ++k) {
    float4 c = ctx[k];
    c.x *= wsc; c.y *= wsc; c.z *= wsc; c.w *= wsc;
    *reinterpret_cast<float4*>(&lds_ctx[wave][4*lane + 256*k]) = c;
  }
  __syncthreads();
  float* outp = ws_ctx + ((size_t)b*16 + chunk)*TWOH;
  for (int d = threadIdx.x; d < TWOH; d += 256)
    outp[d] = lds_ctx[0][d] + lds_ctx[1][d] + lds_ctx[2][d] + lds_ctx[3][d];
  if (threadIdx.x == 0) {
    ws_ms[((size_t)b*16 + chunk)*2]     = M;
    ws_ms[((size_t)b*16 + chunk)*2 + 1] = ssum_c;
  }
}

// K2 v4: parallel combine. Grid (14 kchunks x 64 b), 1 thread = 1 output elem.
__global__ __launch_bounds__(256) void k_combine(const float* __restrict__ ws_ms,
                                                 const float* __restrict__ ws_ctx,
                                                 const float* __restrict__ hidden,
                                                 const float* __restrict__ emb_table,
                                                 const int* __restrict__ x,
                                                 unsigned short* __restrict__ rnnB) {
  const int b = blockIdx.y;
  const int k = blockIdx.x*256 + threadIdx.x;   // 0..3583
  unsigned short* rb = rnnB + (size_t)b*KTOT;

  if (k < TWOH) {
    float mc[16], sc[16];
#pragma unroll
    for (int c = 0; c < 16; ++c) {
      mc[c] = ws_ms[(b*16 + c)*2];
      sc[c] = ws_ms[(b*16 + c)*2 + 1];
    }
    float M = mc[0];
#pragma unroll
    for (int c = 1; c < 16; ++c) M = fmaxf(M, mc[c]);
    float wc[16], Ssum = 0.f;
#pragma unroll
    for (int c = 0; c < 16; ++c) { wc[c] = __expf(mc[c] - M); Ssum += wc[c]*sc[c]; }
    const float inv = 1.f / Ssum;
    float a = 0.f;
#pragma unroll
    for (int c = 0; c < 16; ++c) a += wc[c] * ws_ctx[((size_t)b*16 + c)*TWOH + k];
    rb[k] = f2bf(a * inv);
  } else if (k < KDIM) {
    const int xb = x[b];
    rb[k] = f2bf(emb_table[(size_t)xb*EMB + (k - TWOH)]);
  } else {
    rb[k] = f2bf(hidden[b*HDIM + (k - KDIM)]);
  }
}

// K3 v8: LDS-staged MFMA gate GEMM (v12-style). Block = 64 gate rows x 64
// batch, 4 waves; split-K=8 (448 k each = 7 chunks of 64; KDIM%64==0 so each
// chunk lies wholly in W_ih or W_hh). Row-contiguous staging + XOR-swizzled
// double-buffered LDS. Arithmetic order identical to v5/v7 -> same absmax.
__global__ __launch_bounds__(256) void k_gates(const unsigned short* __restrict__ rnnB,
                                               const float* __restrict__ W_ih,
                                               const float* __restrict__ W_hh,
                                               float* __restrict__ ws_gp) {
  __shared__ unsigned short lds_a[2][64*64];   // 2 x 8KB
  const int tid  = threadIdx.x;
  const int lane = tid & 63;
  const int wave = tid >> 6;
  const int part = blockIdx.x & 7;     // k-part: 448 each
  const int rg   = blockIdx.x >> 3;    // 0..63
  const int j0   = rg*64;              // block's first gate row
  const int mlo  = lane & 15;
  const int kg   = lane >> 4;
  const int srow = tid >> 4;           // staging row 0..15 (+jj*16)
  const int scol = (tid & 15) * 4;     // staging col (floats)

  const unsigned short* rp0 = rnnB + (size_t)mlo*KTOT;

  f32x4 acc0 = {0.f,0.f,0.f,0.f}, acc1 = acc0, acc2 = acc0, acc3 = acc0;
  float4 st[4];

#define G_GLOAD(C)                                                            \
  {                                                                           \
    const int kb = part*448 + (C)*64;                                         \
    _Pragma("unroll")                                                         \
    for (int jj = 0; jj < 4; ++jj) {                                          \
      const int r = j0 + srow + jj*16;                                        \
      const float* wrow = (kb < KDIM)                                         \
          ? (W_ih + (size_t)r*KDIM + kb + scol)                               \
          : (W_hh + (size_t)r*HDIM + (kb - KDIM) + scol);                     \
      st[jj] = *reinterpret_cast<const float4*>(wrow);                        \
    }                                                                         \
  }

#define G_SWRITE(BUF)                                                         \
  _Pragma("unroll")                                                           \
  for (int jj = 0; jj < 4; ++jj) {                                            \
    const int r = srow + jj*16;                                               \
    unsigned short tmp[4];                                                    \
    tmp[0] = f2bf(st[jj].x); tmp[1] = f2bf(st[jj].y);                         \
    tmp[2] = f2bf(st[jj].z); tmp[3] = f2bf(st[jj].w);                         \
    const int boff = r*128 + ((scol*2) ^ ((r & 7) << 4));                     \
    *reinterpret_cast<uint2*>(reinterpret_cast<char*>(lds_a[BUF]) + boff) =   \
        *reinterpret_cast<const uint2*>(tmp);                                 \
  }

  G_GLOAD(0)
  G_SWRITE(0)
  __syncthreads();

  int cur = 0;
  const int arow = wave*16 + mlo;
  const int abase = arow*128;
  const int asw  = (arow & 7) << 4;

  for (int c = 0; c < 7; ++c) {
    if (c < 6) G_GLOAD(c+1)

    const bf16x8 af0 = *reinterpret_cast<const bf16x8*>(
        reinterpret_cast<const char*>(lds_a[cur]) + abase + ((kg*16) ^ asw));
    const bf16x8 af1 = *reinterpret_cast<const bf16x8*>(
        reinterpret_cast<const char*>(lds_a[cur]) + abase + ((64 + kg*16) ^ asw));

    const size_t K0 = (size_t)part*448 + c*64 + kg*8;
    const bf16x8 b00 = *reinterpret_cast<const bf16x8*>(rp0 + K0);
    const bf16x8 b10 = *reinterpret_cast<const bf16x8*>(rp0 + 16*KTOT + K0);
    const bf16x8 b20 = *reinterpret_cast<const bf16x8*>(rp0 + 32*KTOT + K0);
    const bf16x8 b30 = *reinterpret_cast<const bf16x8*>(rp0 + 48*KTOT + K0);
    const bf16x8 b01 = *reinterpret_cast<const bf16x8*>(rp0 + K0 + 32);
    const bf16x8 b11 = *reinterpret_cast<const bf16x8*>(rp0 + 16*KTOT + K0 + 32);
    const bf16x8 b21 = *reinterpret_cast<const bf16x8*>(rp0 + 32*KTOT + K0 + 32);
    const bf16x8 b31 = *reinterpret_cast<const bf16x8*>(rp0 + 48*KTOT + K0 + 32);

    acc0 = __builtin_amdgcn_mfma_f32_16x16x32_bf16(af0, b00, acc0, 0, 0, 0);
    acc1 = __builtin_amdgcn_mfma_f32_16x16x32_bf16(af0, b10, acc1, 0, 0, 0);
    acc2 = __builtin_amdgcn_mfma_f32_16x16x32_bf16(af0, b20, acc2, 0, 0, 0);
    acc3 = __builtin_amdgcn_mfma_f32_16x16x32_bf16(af0, b30, acc3, 0, 0, 0);
    acc0 = __builtin_amdgcn_mfma_f32_16x16x32_bf16(af1, b01, acc0, 0, 0, 0);
    acc1 = __builtin_amdgcn_mfma_f32_16x16x32_bf16(af1, b11, acc1, 0, 0, 0);
    acc2 = __builtin_amdgcn_mfma_f32_16x16x32_bf16(af1, b21, acc2, 0, 0, 0);
    acc3 = __builtin_amdgcn_mfma_f32_16x16x32_bf16(af1, b31, acc3, 0, 0, 0);

    if (c < 6) G_SWRITE(cur ^ 1)
    __syncthreads();
    cur ^= 1;
  }
#undef G_GLOAD
#undef G_SWRITE

  const int mbase = j0 + wave*16 + kg*4;
#define G_ST(ACC, N)                                                          \
  {                                                                           \
    _Pragma("unroll")                                                         \
    for (int jj = 0; jj < 4; ++jj)                                            \
      ws_gp[((size_t)part*4096 + mbase + jj)*64 + ((N)*16 + mlo)] = ACC[jj];  \
  }
  G_ST(acc0, 0) G_ST(acc1, 1) G_ST(acc2, 2) G_ST(acc3, 3)
#undef G_ST
}

// K3b: sum 8 partials + biases, LSTM pointwise; emit h as f32 outs + bf16 hB.
__global__ __launch_bounds__(256) void k_lstm(const float* __restrict__ ws_gp,
                                              const float* __restrict__ b_ih,
                                              const float* __restrict__ b_hh,
                                              const float* __restrict__ cell,
                                              float* __restrict__ out_h,
                                              float* __restrict__ out_c,
                                              unsigned short* __restrict__ hB) {
  const int id = blockIdx.x*256 + threadIdx.x;  // 65536
  const int h = id >> 6, b = id & 63;
  float g[4];
#pragma unroll
  for (int gg = 0; gg < 4; ++gg) {
    const int j = gg*1024 + h;
    float v = b_ih[j] + b_hh[j];
#pragma unroll
    for (int p = 0; p < 8; ++p) v += ws_gp[((size_t)p*4096 + j)*64 + b];
    g[gg] = v;
  }
  const float iv = sigmoidf_(g[0]);
  const float fv = sigmoidf_(g[1]);
  const float gv = tanhf(g[2]);
  const float ov = sigmoidf_(g[3]);
  const float cold = cell[b*HDIM + h];
  const float cn = fmaf(fv, cold, iv*gv);
  const float hn = ov * tanhf(cn);
  out_h[b*HDIM + h] = hn;
  out_c[b*HDIM + h] = cn;
  hB[(size_t)b*HDIM + h] = f2bf(hn);
}

// K4 v12: LDS-staged MFMA fc GEMM (unchanged from R20 — confirmed win).
__global__ __launch_bounds__(256) void k_fc(const unsigned short* __restrict__ hB,
                                            const float* __restrict__ fc_W,
                                            const float* __restrict__ fc_b,
                                            float* __restrict__ preds) {
  __shared__ unsigned short lds_a[2][64*64];   // 2 x 8KB
  const int tid  = threadIdx.x;
  const int lane = tid & 63;
  const int wave = tid >> 6;
  const int row0b = blockIdx.x * 64;           // grid 500 -> 32000 rows
  const int mlo  = lane & 15;
  const int kg   = lane >> 4;
  const int srow = tid >> 4;                   // staging row 0..15 (+j*16)
  const int scol = (tid & 15) * 4;             // staging col (floats)

  const unsigned short* hp = hB + (size_t)mlo*HDIM + kg*8;

  f32x4 acc0 = {0.f,0.f,0.f,0.f}, acc1 = acc0, acc2 = acc0, acc3 = acc0;
  float4 st[4];

#define FC_GLOAD(C)                                                           \
  _Pragma("unroll")                                                           \
  for (int jj = 0; jj < 4; ++jj)                                              \
    st[jj] = *reinterpret_cast<const float4*>(                                \
        fc_W + (size_t)(row0b + srow + jj*16)*HDIM + (C)*64 + scol);

#define FC_SWRITE(BUF)                                                        \
  _Pragma("unroll")                                                           \
  for (int jj = 0; jj < 4; ++jj) {                                            \
    const int r = srow + jj*16;                                               \
    unsigned short tmp[4];                                                    \
    tmp[0] = f2bf(st[jj].x); tmp[1] = f2bf(st[jj].y);                         \
    tmp[2] = f2bf(st[jj].z); tmp[3] = f2bf(st[jj].w);                         \
    const int boff = r*128 + ((scol*2) ^ ((r & 7) << 4));                     \
    *reinterpret_cast<uint2*>(reinterpret_cast<char*>(lds_a[BUF]) + boff) =   \
        *reinterpret_cast<const uint2*>(tmp);                                 \
  }

  FC_GLOAD(0)
  FC_SWRITE(0)
  __syncthreads();

  int cur = 0;
  const int arow = wave*16 + mlo;
  const int abase = arow*128;
  const int asw  = (arow & 7) << 4;

  for (int c = 0; c < 16; ++c) {
    if (c < 15) FC_GLOAD(c+1)

    const bf16x8 af0 = *reinterpret_cast<const bf16x8*>(
        reinterpret_cast<const char*>(lds_a[cur]) + abase + ((kg*16) ^ asw));
    const bf16x8 af1 = *reinterpret_cast<const bf16x8*>(
        reinterpret_cast<const char*>(lds_a[cur]) + abase + ((64 + kg*16) ^ asw));

    const int K0 = c*64;
    const bf16x8 b00 = *reinterpret_cast<const bf16x8*>(hp + K0);
    const bf16x8 b10 = *reinterpret_cast<const bf16x8*>(hp + 16*HDIM + K0);
    const bf16x8 b20 = *reinterpret_cast<const bf16x8*>(hp + 32*HDIM + K0);
    const bf16x8 b30 = *reinterpret_cast<const bf16x8*>(hp + 48*HDIM + K0);
    const bf16x8 b01 = *reinterpret_cast<const bf16x8*>(hp + K0 + 32);
    const bf16x8 b11 = *reinterpret_cast<const bf16x8*>(hp + 16*HDIM + K0 + 32);
    const bf16x8 b21 = *reinterpret_cast<const bf16x8*>(hp + 32*HDIM + K0 + 32);
    const bf16x8 b31 = *reinterpret_cast<const bf16x8*>(hp + 48*HDIM + K0 + 32);

    acc0 = __builtin_amdgcn_mfma_f32_16x16x32_bf16(af0, b00, acc0, 0, 0, 0);
    acc1 = __builtin_amdgcn_mfma_f32_16x16x32_bf16(af0, b10, acc1, 0, 0, 0);
    acc2 = __builtin_amdgcn_mfma_f32_16x16x32_bf16(af0, b20, acc2, 0, 0, 0);
    acc3 = __builtin_amdgcn_mfma_f32_16x16x32_bf16(af0, b30, acc3, 0, 0, 0);
    acc0 = __builtin_amdgcn_mfma_f32_16x16x32_bf16(af1, b01, acc0, 0, 0, 0);
    acc1 = __builtin_amdgcn_mfma_f32_16x16x32_bf16(af1, b11, acc1, 0, 0, 0);
    acc2 = __builtin_amdgcn_mfma_f32_16x16x32_bf16(af1, b21, acc2, 0, 0, 0);
    acc3 = __builtin_amdgcn_mfma_f32_16x16x32_bf16(af1, b31, acc3, 0, 0, 0);

    if (c < 15) FC_SWRITE(cur ^ 1)
    __syncthreads();
    cur ^= 1;
  }
#undef FC_GLOAD
#undef FC_SWRITE

  const int mbase = row0b + wave*16 + kg*4;
  const float4 bias = make_float4(fc_b[mbase], fc_b[mbase+1],
                                  fc_b[mbase+2], fc_b[mbase+3]);
#define FC_STORE(ACC, N)                                                      \
  {                                                                           \
    float4 stv = make_float4(ACC[0] + bias.x, ACC[1] + bias.y,                \
                             ACC[2] + bias.z, ACC[3] + bias.w);               \
    *reinterpret_cast<float4*>(preds + (size_t)((N)*16 + mlo)*VOUT + mbase) = stv; \
  }
  FC_STORE(acc0, 0) FC_STORE(acc1, 1) FC_STORE(acc2, 2) FC_STORE(acc3, 3)
#undef FC_STORE
}

extern "C" void kernel_launch(void* const* d_in, const int* in_sizes, int n_in,
                              void* d_out, int out_size, void* d_ws, size_t ws_size,
                              hipStream_t stream) {
  const int*   x      = (const int*)  d_in[0];
  const float* enc    = (const float*)d_in[1];
  const float* hidden = (const float*)d_in[2];
  const float* cell   = (const float*)d_in[3];
  const float* embt   = (const float*)d_in[4];
  const float* eW     = (const float*)d_in[5];
  const float* eb     = (const float*)d_in[6];
  const float* W_ih   = (const float*)d_in[7];
  const float* W_hh   = (const float*)d_in[8];
  const float* b_ih   = (const float*)d_in[9];
  const float* b_hh   = (const float*)d_in[10];
  const float* fc_W   = (const float*)d_in[11];
  const float* fc_b   = (const float*)d_in[12];

  float* out   = (float*)d_out;
  float* preds = out;                              // 64*32000
  float* out_h = out + (size_t)BATCH*VOUT;         // 64*1024
  float* out_c = out_h + BATCH*HDIM;               // 64*1024
  float* ws    = (float*)d_ws;
  unsigned short* rnnB = (unsigned short*)(ws + WS_RNNB);
  unsigned short* hB   = (unsigned short*)(ws + WS_HB16);

  k_attn<<<dim3(16, 64), 256, 0, stream>>>(enc, eW, eb, hidden, ws + WS_MS, ws + WS_CTX);
  k_combine<<<dim3(14, 64), 256, 0, stream>>>(ws + WS_MS, ws + WS_CTX, hidden, embt, x, rnnB);
  k_gates<<<512, 256, 0, stream>>>(rnnB, W_ih, W_hh, ws + WS_GP);
  k_lstm<<<256, 256, 0, stream>>>(ws + WS_GP, b_ih, b_hh, cell, out_h, out_c, hB);
  k_fc<<<500, 256, 0, stream>>>(hB, fc_W, fc_b, preds);
}